// Round 1
// baseline (3555.387 us; speedup 1.0000x reference)
//
#include <hip/hip_runtime.h>

#define DPDIM 32         // path/link state dim
#define GCOLS 96         // 3*DPDIM gate columns
#define PLEN 8
#define T_ITERS 8
#define RUNITS 256

// ---------------- fast activations (v_exp_f32 + v_rcp_f32) ----------------
__device__ __forceinline__ float fast_sigmoid(float a) {
    return __builtin_amdgcn_rcpf(1.0f + __expf(-a));
}
__device__ __forceinline__ float fast_tanh(float a) {
    // tanh(x) = 1 - 2/(1+e^{2x}); stable at both infinities
    return 1.0f - 2.0f * __builtin_amdgcn_rcpf(1.0f + __expf(2.0f * a));
}

#define ACC4(a0,a1,a2,a3, s, V) \
    a0 = fmaf((s), (V).x, a0); a1 = fmaf((s), (V).y, a1); \
    a2 = fmaf((s), (V).z, a2); a3 = fmaf((s), (V).w, a3);

#define ACC4F(A, s, V) \
    A.x = fmaf((s), (V).x, A.x); A.y = fmaf((s), (V).y, A.y); \
    A.z = fmaf((s), (V).z, A.z); A.w = fmaf((s), (V).w, A.w);

// ---------------- full GRU step (used by link_kernel only) ----------------
template<int STRIDE>
__device__ __forceinline__ void gru_step(
    float* __restrict__ h, const float* __restrict__ x,
    const float* __restrict__ sW, const float* __restrict__ sU,
    const float* __restrict__ sbi, const float* __restrict__ sbh,
    float* __restrict__ hl)
{
    for (int jb = 0; jb < 8; ++jb) {
        float az0=0.f,az1=0.f,az2=0.f,az3=0.f;
        float ar0=0.f,ar1=0.f,ar2=0.f,ar3=0.f;
        float ai0=0.f,ai1=0.f,ai2=0.f,ai3=0.f;
        float ah0=0.f,ah1=0.f,ah2=0.f,ah3=0.f;
        const float* wp = sW + jb*4;
        const float* up = sU + jb*4;
        #pragma unroll
        for (int k = 0; k < DPDIM; ++k) {
            const float xk = x[k], hk = h[k];
            const float4 WZ = *(const float4*)(wp + k*GCOLS);
            const float4 WR = *(const float4*)(wp + k*GCOLS + 32);
            const float4 WH = *(const float4*)(wp + k*GCOLS + 64);
            const float4 UZ = *(const float4*)(up + k*GCOLS);
            const float4 UR = *(const float4*)(up + k*GCOLS + 32);
            const float4 UH = *(const float4*)(up + k*GCOLS + 64);
            ACC4(az0,az1,az2,az3, xk, WZ); ACC4(az0,az1,az2,az3, hk, UZ);
            ACC4(ar0,ar1,ar2,ar3, xk, WR); ACC4(ar0,ar1,ar2,ar3, hk, UR);
            ACC4(ai0,ai1,ai2,ai3, xk, WH);
            ACC4(ah0,ah1,ah2,ah3, hk, UH);
        }
        const float4 BZI = *(const float4*)(sbi + jb*4);
        const float4 BRI = *(const float4*)(sbi + 32 + jb*4);
        const float4 BHI = *(const float4*)(sbi + 64 + jb*4);
        const float4 BZH = *(const float4*)(sbh + jb*4);
        const float4 BRH = *(const float4*)(sbh + 32 + jb*4);
        const float4 BHH = *(const float4*)(sbh + 64 + jb*4);
        float* hq = hl + (jb*4)*STRIDE;
        {
            float z = fast_sigmoid(az0 + BZI.x + BZH.x);
            float r = fast_sigmoid(ar0 + BRI.x + BRH.x);
            float c = fast_tanh(ai0 + BHI.x + r * (ah0 + BHH.x));
            float ho = hq[0*STRIDE]; hq[0*STRIDE] = z*ho + (1.f - z)*c;
        }
        {
            float z = fast_sigmoid(az1 + BZI.y + BZH.y);
            float r = fast_sigmoid(ar1 + BRI.y + BRH.y);
            float c = fast_tanh(ai1 + BHI.y + r * (ah1 + BHH.y));
            float ho = hq[1*STRIDE]; hq[1*STRIDE] = z*ho + (1.f - z)*c;
        }
        {
            float z = fast_sigmoid(az2 + BZI.z + BZH.z);
            float r = fast_sigmoid(ar2 + BRI.z + BRH.z);
            float c = fast_tanh(ai2 + BHI.z + r * (ah2 + BHH.z));
            float ho = hq[2*STRIDE]; hq[2*STRIDE] = z*ho + (1.f - z)*c;
        }
        {
            float z = fast_sigmoid(az3 + BZI.w + BZH.w);
            float r = fast_sigmoid(ar3 + BRI.w + BRH.w);
            float c = fast_tanh(ai3 + BHI.w + r * (ah3 + BHH.w));
            float ho = hq[3*STRIDE]; hq[3*STRIDE] = z*ho + (1.f - z)*c;
        }
    }
    #pragma unroll
    for (int j = 0; j < DPDIM; ++j) h[j] = hl[j*STRIDE];
}

// ---------------- init states ----------------
__global__ __launch_bounds__(256) void init_kernel(
    const float* __restrict__ traffic, const float* __restrict__ packets,
    const float* __restrict__ eqlam, const float* __restrict__ avgpkt,
    const float* __restrict__ capacity, const float* __restrict__ queues,
    float* __restrict__ path_state, float* __restrict__ link_state,
    int n_paths, int n_links)
{
    int i = blockIdx.x * 256 + threadIdx.x;
    if (i < n_paths) {
        float4* row = (float4*)(path_state + (size_t)i * DPDIM);
        row[0] = make_float4(traffic[i], packets[i], eqlam[i], avgpkt[i]);
        float4 z = make_float4(0.f, 0.f, 0.f, 0.f);
        #pragma unroll
        for (int k = 1; k < 8; ++k) row[k] = z;
    }
    if (i < n_links) {
        float4* row = (float4*)(link_state + (size_t)i * DPDIM);
        row[0] = make_float4(capacity[i], queues[i], 0.f, 0.f);
        float4 z = make_float4(0.f, 0.f, 0.f, 0.f);
        #pragma unroll
        for (int k = 1; k < 8; ++k) row[k] = z;
    }
}

// ---------------- weight transpose: Up[k][96] -> UpT[jb][k][12] ------------
// UpT[((jb*32)+k)*12 + idx], idx 0..3 = z cols jb*4+c, 4..7 = r, 8..11 = h
__global__ __launch_bounds__(256) void transpose_up_kernel(
    const float* __restrict__ Up, float* __restrict__ UpT)
{
    int i = blockIdx.x * 256 + threadIdx.x;
    if (i >= 8*32*12) return;
    int idx = i % 12;
    int k   = (i / 12) % 32;
    int jb  = i / (12*32);
    int gate = idx >> 2, c = idx & 3;
    UpT[i] = Up[k*GCOLS + gate*32 + jb*4 + c];
}

// ---------------- CSR build ----------------
__global__ __launch_bounds__(256) void zero_counts_kernel(int* __restrict__ counts, int n) {
    int i = blockIdx.x * 256 + threadIdx.x;
    if (i < n) counts[i] = 0;
}
__global__ __launch_bounds__(256) void hist_kernel(
    const int* __restrict__ link_to_path, int* __restrict__ counts, int n) {
    int i = blockIdx.x * 256 + threadIdx.x;
    if (i < n) atomicAdd(&counts[link_to_path[i]], 1);
}
__global__ __launch_bounds__(1024) void scan_kernel(
    const int* __restrict__ counts, int* __restrict__ offsets,
    int* __restrict__ cursor, int n)
{
    __shared__ int s[1024];
    int t = threadIdx.x;
    int chunk = (n + 1023) >> 10;
    int lo = t * chunk;
    int hi = lo + chunk; if (hi > n) hi = n;
    int local = 0;
    for (int i = lo; i < hi; ++i) local += counts[i];
    s[t] = local;
    __syncthreads();
    for (int d = 1; d < 1024; d <<= 1) {
        int v = (t >= d) ? s[t - d] : 0;
        __syncthreads();
        s[t] += v;
        __syncthreads();
    }
    int base = (t > 0) ? s[t - 1] : 0;
    for (int i = lo; i < hi; ++i) {
        offsets[i] = base; cursor[i] = base; base += counts[i];
    }
    if (t == 1023) offsets[n] = s[1023];
}
__global__ __launch_bounds__(256) void fill_kernel(
    const int* __restrict__ link_to_path, int* __restrict__ cursor,
    int* __restrict__ entries, int n) {
    int e = blockIdx.x * 256 + threadIdx.x;
    if (e < n) {
        int l = link_to_path[e];
        int pos = atomicAdd(&cursor[l], 1);
        entries[pos] = e >> 3;   // path id (PLEN == 8)
    }
}

// ---------------- per-link input-gate precompute ---------------------------
// Gi_z = x@Wz + biz + bhz ; Gi_r = x@Wr + bir + bhr ; Gi_h = x@Wh + bih
__global__ __launch_bounds__(128) void gate_pre_kernel(
    const float* __restrict__ link_state,
    const float* __restrict__ Wp, const float* __restrict__ bip,
    const float* __restrict__ bhp,
    float* __restrict__ Gi, int* __restrict__ nzf, int n_links)
{
    __shared__ __align__(16) float sW[DPDIM*GCOLS];
    __shared__ __align__(16) float sbi[GCOLS];
    __shared__ __align__(16) float sbh[GCOLS];
    int t = threadIdx.x;
    for (int i = t; i < DPDIM*GCOLS; i += 128) sW[i] = Wp[i];
    if (t < GCOLS) { sbi[t] = bip[t]; sbh[t] = bhp[t]; }
    __syncthreads();
    int l = blockIdx.x * 128 + t;
    if (l >= n_links) return;
    float x[DPDIM];
    bool nz = false;
    const float4* row = (const float4*)(link_state + (size_t)l * DPDIM);
    #pragma unroll
    for (int k = 0; k < 8; ++k) {
        float4 v = row[k];
        x[4*k+0]=v.x; x[4*k+1]=v.y; x[4*k+2]=v.z; x[4*k+3]=v.w;
        nz = nz || (v.x != 0.f) || (v.y != 0.f) || (v.z != 0.f) || (v.w != 0.f);
    }
    float* G = Gi + (size_t)l * GCOLS;
    #pragma unroll 1
    for (int jb = 0; jb < 8; ++jb) {
        float4 az = {0,0,0,0}, ar = {0,0,0,0}, ah = {0,0,0,0};
        const float* wp = sW + jb*4;
        #pragma unroll
        for (int k = 0; k < DPDIM; ++k) {
            const float xk = x[k];
            const float4 WZ = *(const float4*)(wp + k*GCOLS);
            const float4 WR = *(const float4*)(wp + k*GCOLS + 32);
            const float4 WH = *(const float4*)(wp + k*GCOLS + 64);
            ACC4F(az, xk, WZ); ACC4F(ar, xk, WR); ACC4F(ah, xk, WH);
        }
        const float4 bz = *(const float4*)(sbi + jb*4);
        const float4 br = *(const float4*)(sbi + 32 + jb*4);
        const float4 bh = *(const float4*)(sbi + 64 + jb*4);
        const float4 cz = *(const float4*)(sbh + jb*4);
        const float4 cr = *(const float4*)(sbh + 32 + jb*4);
        *(float4*)(G + jb*4)      = make_float4(az.x+bz.x+cz.x, az.y+bz.y+cz.y,
                                                az.z+bz.z+cz.z, az.w+bz.w+cz.w);
        *(float4*)(G + 32 + jb*4) = make_float4(ar.x+br.x+cr.x, ar.y+br.y+cr.y,
                                                ar.z+br.z+cr.z, ar.w+br.w+cr.w);
        *(float4*)(G + 64 + jb*4) = make_float4(ah.x+bh.x, ah.y+bh.y, ah.z+bh.z, ah.w+bh.w);
    }
    nzf[l] = nz ? 1 : 0;
}

// ---------------- path GRU: h fully register-resident ----------------------
// One thread per path. h[32] + hn[32] live in VGPRs (all indexing static via
// full unroll) -> zero LDS, no ds_read on the critical path. Weights stay
// wave-uniform (s_load). Grid gives only ~1.5 waves/SIMD, so the per-wave
// critical path is what matters: previously ds_read(h) serialized against
// the FMA chain every k; now h feeds FMAs directly from VGPRs.
__global__ __launch_bounds__(64, 1) void path_kernel(
    const float* __restrict__ Gi, const int* __restrict__ nzf,
    float* __restrict__ path_state, const int* __restrict__ link_to_path,
    const float* __restrict__ UpT, const float* __restrict__ bhp, int n_paths)
{
    int t = threadIdx.x;
    int p = blockIdx.x * 64 + t;
    bool act = p < n_paths;
    int pp = act ? p : (n_paths - 1);

    float h[DPDIM];
    {
        const float4* row = (const float4*)(path_state + (size_t)pp * DPDIM);
        #pragma unroll
        for (int k4 = 0; k4 < 8; ++k4) {
            float4 v = row[k4];
            h[4*k4+0]=v.x; h[4*k4+1]=v.y; h[4*k4+2]=v.z; h[4*k4+3]=v.w;
        }
    }
    // preload the 8 link ids (contiguous: two int4 loads)
    int links[PLEN];
    {
        const int4* lp = (const int4*)(link_to_path + (size_t)pp * PLEN);
        int4 a = lp[0], b = lp[1];
        links[0]=a.x; links[1]=a.y; links[2]=a.z; links[3]=a.w;
        links[4]=b.x; links[5]=b.y; links[6]=b.z; links[7]=b.w;
    }

    #pragma unroll 1
    for (int s = 0; s < PLEN; ++s) {
        int l = links[s];
        bool nz = nzf[l] != 0;
        const float* G = Gi + (size_t)l * GCOLS;
        float hn[DPDIM];
        #pragma unroll
        for (int jb = 0; jb < 8; ++jb) {
            float4 az  = *(const float4*)(G + jb*4);
            float4 ar  = *(const float4*)(G + 32 + jb*4);
            float4 gih = *(const float4*)(G + 64 + jb*4);
            float4 ah  = *(const float4*)(bhp + 64 + jb*4);   // uniform
            const float* w = UpT + jb*(32*12);
            #pragma unroll
            for (int k = 0; k < DPDIM; ++k) {
                float hk = h[k];
                const float4 wz = *(const float4*)(w);
                const float4 wr = *(const float4*)(w + 4);
                const float4 wh = *(const float4*)(w + 8);
                ACC4F(az, hk, wz); ACC4F(ar, hk, wr); ACC4F(ah, hk, wh);
                w += 12;
            }
#define PWC(C, j) { \
            float zz = fast_sigmoid(az.C); \
            float rr = fast_sigmoid(ar.C); \
            float cc = fast_tanh(gih.C + rr * ah.C); \
            hn[jb*4+j] = cc + zz * (h[jb*4+j] - cc); }
            PWC(x, 0) PWC(y, 1) PWC(z, 2) PWC(w, 3)
#undef PWC
        }
        #pragma unroll
        for (int k = 0; k < DPDIM; ++k) h[k] = nz ? hn[k] : h[k];
    }

    if (act) {
        float4* row = (float4*)(path_state + (size_t)p * DPDIM);
        #pragma unroll
        for (int k4 = 0; k4 < 8; ++k4)
            row[k4] = make_float4(h[4*k4+0], h[4*k4+1], h[4*k4+2], h[4*k4+3]);
    }
}

// ---------------- segment sum: path states -> per-link sums ----------------
__global__ __launch_bounds__(256) void seg_sum_kernel(
    const float* __restrict__ path_state, const int* __restrict__ offsets,
    const int* __restrict__ entries, float* __restrict__ path_sum, int n_links)
{
    int t = threadIdx.x;
    int d = t & 31, li = t >> 5;        // 8 links per block, 32 dims each
    int l = blockIdx.x * 8 + li;
    if (l >= n_links) return;
    int beg = offsets[l], end = offsets[l+1];
    float a0 = 0.f, a1 = 0.f, a2 = 0.f, a3 = 0.f;
    int q = beg;
    for (; q + 3 < end; q += 4) {
        int p0 = entries[q], p1 = entries[q+1], p2 = entries[q+2], p3 = entries[q+3];
        a0 += path_state[(size_t)p0 * DPDIM + d];
        a1 += path_state[(size_t)p1 * DPDIM + d];
        a2 += path_state[(size_t)p2 * DPDIM + d];
        a3 += path_state[(size_t)p3 * DPDIM + d];
    }
    for (; q < end; ++q)
        a0 += path_state[(size_t)entries[q] * DPDIM + d];
    path_sum[(size_t)l * DPDIM + d] = (a0 + a1) + (a2 + a3);
}

// ---------------- link GRU: one step, x = path_sum -------------------------
__global__ __launch_bounds__(128, 1) void link_kernel(
    const float* __restrict__ path_sum, float* __restrict__ link_state,
    const float* __restrict__ Wl, const float* __restrict__ Ul,
    const float* __restrict__ bil, const float* __restrict__ bhl, int n_links)
{
    __shared__ __align__(16) float sW[DPDIM*GCOLS];
    __shared__ __align__(16) float sU[DPDIM*GCOLS];
    __shared__ __align__(16) float sbi[GCOLS];
    __shared__ __align__(16) float sbh[GCOLS];
    __shared__ float h_lds[DPDIM * 128];
    int t = threadIdx.x;
    for (int i = t; i < DPDIM*GCOLS; i += 128) { sW[i] = Wl[i]; sU[i] = Ul[i]; }
    for (int i = t; i < GCOLS; i += 128)       { sbi[i] = bil[i]; sbh[i] = bhl[i]; }
    int l = blockIdx.x * 128 + t;
    bool active = l < n_links;
    float h[DPDIM], x[DPDIM];
    if (active) {
        const float4* hrow = (const float4*)(link_state + (size_t)l * DPDIM);
        const float4* xrow = (const float4*)(path_sum + (size_t)l * DPDIM);
        #pragma unroll
        for (int k = 0; k < 8; ++k) {
            float4 v = hrow[k];
            h[4*k+0]=v.x; h[4*k+1]=v.y; h[4*k+2]=v.z; h[4*k+3]=v.w;
            float4 u = xrow[k];
            x[4*k+0]=u.x; x[4*k+1]=u.y; x[4*k+2]=u.z; x[4*k+3]=u.w;
        }
    } else {
        #pragma unroll
        for (int k = 0; k < DPDIM; ++k) { h[k] = 0.f; x[k] = 0.f; }
    }
    #pragma unroll
    for (int j = 0; j < DPDIM; ++j) h_lds[j*128 + t] = h[j];
    __syncthreads();
    if (active) {
        gru_step<128>(h, x, sW, sU, sbi, sbh, &h_lds[t]);
        float4* row = (float4*)(link_state + (size_t)l * DPDIM);
        #pragma unroll
        for (int k = 0; k < 8; ++k)
            row[k] = make_float4(h[4*k+0], h[4*k+1], h[4*k+2], h[4*k+3]);
    }
}

// ---------------- readout: relu(ls@W1+b1) -> relu(@W2+b2) -> @W3+b3 --------
__global__ __launch_bounds__(256) void readout_kernel(
    const float* __restrict__ link_state,
    const float* __restrict__ W1, const float* __restrict__ b1,
    const float* __restrict__ W2, const float* __restrict__ b2,
    const float* __restrict__ W3, const float* __restrict__ b3,
    float* __restrict__ out, int n_links)
{
    __shared__ __align__(16) float s_ls[64*DPDIM];   // 8 KB
    __shared__ float s_m[64*257];                    // 64.25 KB (r1, then r2*w3)
    __shared__ float s_part[256];
    __shared__ float s_w3[RUNITS];
    int t = threadIdx.x;
    int l0 = blockIdx.x * 64;
    int nl = n_links - l0; if (nl > 64) nl = 64;
    for (int i = t; i < nl*DPDIM; i += 256) s_ls[i] = link_state[(size_t)l0*DPDIM + i];
    s_w3[t] = W3[t];
    __syncthreads();
    // r1 = relu(ls @ W1 + b1) ; thread t owns column t
    float w1c[DPDIM];
    #pragma unroll
    for (int k = 0; k < DPDIM; ++k) w1c[k] = W1[k*RUNITS + t];
    float b1t = b1[t];
    for (int i = 0; i < nl; ++i) {
        float a = b1t;
        #pragma unroll
        for (int k = 0; k < DPDIM; ++k) a = fmaf(s_ls[i*DPDIM + k], w1c[k], a);
        s_m[i*257 + t] = fmaxf(a, 0.f);
    }
    __syncthreads();
    // r2 accum: acc[i] = sum_k r1[i][k] * W2[k][t]   (broadcast LDS reads)
    float acc[64];
    #pragma unroll
    for (int i = 0; i < 64; ++i) acc[i] = 0.f;
    for (int k = 0; k < RUNITS; ++k) {
        float w = W2[k*RUNITS + t];
        #pragma unroll
        for (int i = 0; i < 64; ++i) acc[i] = fmaf(s_m[i*257 + k], w, acc[i]);
    }
    __syncthreads();
    // store relu(acc+b2)*w3 back into s_m
    float b2t = b2[t];
    #pragma unroll
    for (int i = 0; i < 64; ++i)
        s_m[i*257 + t] = fmaxf(acc[i] + b2t, 0.f) * s_w3[t];
    __syncthreads();
    // reduce 256 cols per link: thread t handles link i=t>>2, quarter q=t&3
    {
        int i = t >> 2, q = t & 3;
        float ssum = 0.f;
        for (int j = q*64; j < q*64 + 64; ++j) ssum += s_m[i*257 + j];
        s_part[t] = ssum;
    }
    __syncthreads();
    if (t < nl)
        out[l0 + t] = b3[0] + s_part[t*4] + s_part[t*4+1] + s_part[t*4+2] + s_part[t*4+3];
}

// ---------------- launch ----------------
extern "C" void kernel_launch(void* const* d_in, const int* in_sizes, int n_in,
                              void* d_out, int out_size, void* d_ws, size_t ws_size,
                              hipStream_t stream)
{
    const float* traffic  = (const float*)d_in[0];
    const float* packets  = (const float*)d_in[1];
    const float* eqlam    = (const float*)d_in[2];
    const float* avgpkt   = (const float*)d_in[3];
    const float* capacity = (const float*)d_in[4];
    const float* queues   = (const float*)d_in[5];
    const int* link_to_path = (const int*)d_in[6];
    const float* Wp  = (const float*)d_in[13];
    const float* Up  = (const float*)d_in[14];
    const float* bip = (const float*)d_in[15];
    const float* bhp = (const float*)d_in[16];
    const float* Wl  = (const float*)d_in[17];
    const float* Ul  = (const float*)d_in[18];
    const float* bil = (const float*)d_in[19];
    const float* bhl = (const float*)d_in[20];
    const float* W1  = (const float*)d_in[21];
    const float* b1  = (const float*)d_in[22];
    const float* W2  = (const float*)d_in[23];
    const float* b2  = (const float*)d_in[24];
    const float* W3  = (const float*)d_in[25];
    const float* b3  = (const float*)d_in[26];
    const int n_paths = in_sizes[0];     // 100000
    const int n_links = in_sizes[4];     // 20000
    const int n_ent   = in_sizes[6];     // 800000

    char* ws = (char*)d_ws;
    size_t off = 0;
    auto salloc = [&](size_t bytes) -> void* {
        void* p = ws + off;
        off += (bytes + 255) & ~size_t(255);
        return p;
    };
    float* path_state = (float*)salloc((size_t)n_paths * DPDIM * 4);
    float* link_state = (float*)salloc((size_t)n_links * DPDIM * 4);
    float* Gi         = (float*)salloc((size_t)n_links * GCOLS * 4);
    float* path_sum   = Gi;
    float* UpT    = (float*)salloc((size_t)8 * 32 * 12 * 4);
    int* nzf     = (int*)salloc((size_t)n_links * 4);
    int* counts  = (int*)salloc((size_t)n_links * 4);
    int* offsets = (int*)salloc((size_t)(n_links + 1) * 4);
    int* cursor  = (int*)salloc((size_t)n_links * 4);
    int* entries = (int*)salloc((size_t)n_ent * 4);
    (void)ws_size; (void)n_in; (void)out_size;

    int gmax = ( (n_paths > n_links ? n_paths : n_links) + 255 ) / 256;
    zero_counts_kernel<<<(n_links + 255)/256, 256, 0, stream>>>(counts, n_links);
    init_kernel<<<gmax, 256, 0, stream>>>(traffic, packets, eqlam, avgpkt,
                                          capacity, queues, path_state, link_state,
                                          n_paths, n_links);
    transpose_up_kernel<<<(8*32*12 + 255)/256, 256, 0, stream>>>(Up, UpT);
    hist_kernel<<<(n_ent + 255)/256, 256, 0, stream>>>(link_to_path, counts, n_ent);
    scan_kernel<<<1, 1024, 0, stream>>>(counts, offsets, cursor, n_links);
    fill_kernel<<<(n_ent + 255)/256, 256, 0, stream>>>(link_to_path, cursor, entries, n_ent);

    for (int it = 0; it < T_ITERS; ++it) {
        gate_pre_kernel<<<(n_links + 127)/128, 128, 0, stream>>>(
            link_state, Wp, bip, bhp, Gi, nzf, n_links);
        path_kernel<<<(n_paths + 63)/64, 64, 0, stream>>>(
            Gi, nzf, path_state, link_to_path, UpT, bhp, n_paths);
        seg_sum_kernel<<<(n_links + 7)/8, 256, 0, stream>>>(
            path_state, offsets, entries, path_sum, n_links);
        link_kernel<<<(n_links + 127)/128, 128, 0, stream>>>(
            path_sum, link_state, Wl, Ul, bil, bhl, n_links);
    }
    readout_kernel<<<(n_links + 63)/64, 256, 0, stream>>>(
        link_state, W1, b1, W2, b2, W3, b3, (float*)d_out, n_links);
}

// Round 2
// 2254.415 us; speedup vs baseline: 1.5771x; 1.5771x over previous
//
#include <hip/hip_runtime.h>

#define DPDIM 32         // path/link state dim
#define GCOLS 96         // 3*DPDIM gate columns
#define PLEN 8
#define T_ITERS 8
#define RUNITS 256

// ---------------- fast activations (v_exp_f32 + v_rcp_f32) ----------------
__device__ __forceinline__ float fast_sigmoid(float a) {
    return __builtin_amdgcn_rcpf(1.0f + __expf(-a));
}
__device__ __forceinline__ float fast_tanh(float a) {
    // tanh(x) = 1 - 2/(1+e^{2x}); stable at both infinities
    return 1.0f - 2.0f * __builtin_amdgcn_rcpf(1.0f + __expf(2.0f * a));
}

#define ACC4(a0,a1,a2,a3, s, V) \
    a0 = fmaf((s), (V).x, a0); a1 = fmaf((s), (V).y, a1); \
    a2 = fmaf((s), (V).z, a2); a3 = fmaf((s), (V).w, a3);

#define ACC4F(A, s, V) \
    A.x = fmaf((s), (V).x, A.x); A.y = fmaf((s), (V).y, A.y); \
    A.z = fmaf((s), (V).z, A.z); A.w = fmaf((s), (V).w, A.w);

// ---------------- full GRU step (used by link_kernel only) ----------------
template<int STRIDE>
__device__ __forceinline__ void gru_step(
    float* __restrict__ h, const float* __restrict__ x,
    const float* __restrict__ sW, const float* __restrict__ sU,
    const float* __restrict__ sbi, const float* __restrict__ sbh,
    float* __restrict__ hl)
{
    for (int jb = 0; jb < 8; ++jb) {
        float az0=0.f,az1=0.f,az2=0.f,az3=0.f;
        float ar0=0.f,ar1=0.f,ar2=0.f,ar3=0.f;
        float ai0=0.f,ai1=0.f,ai2=0.f,ai3=0.f;
        float ah0=0.f,ah1=0.f,ah2=0.f,ah3=0.f;
        const float* wp = sW + jb*4;
        const float* up = sU + jb*4;
        #pragma unroll
        for (int k = 0; k < DPDIM; ++k) {
            const float xk = x[k], hk = h[k];
            const float4 WZ = *(const float4*)(wp + k*GCOLS);
            const float4 WR = *(const float4*)(wp + k*GCOLS + 32);
            const float4 WH = *(const float4*)(wp + k*GCOLS + 64);
            const float4 UZ = *(const float4*)(up + k*GCOLS);
            const float4 UR = *(const float4*)(up + k*GCOLS + 32);
            const float4 UH = *(const float4*)(up + k*GCOLS + 64);
            ACC4(az0,az1,az2,az3, xk, WZ); ACC4(az0,az1,az2,az3, hk, UZ);
            ACC4(ar0,ar1,ar2,ar3, xk, WR); ACC4(ar0,ar1,ar2,ar3, hk, UR);
            ACC4(ai0,ai1,ai2,ai3, xk, WH);
            ACC4(ah0,ah1,ah2,ah3, hk, UH);
        }
        const float4 BZI = *(const float4*)(sbi + jb*4);
        const float4 BRI = *(const float4*)(sbi + 32 + jb*4);
        const float4 BHI = *(const float4*)(sbi + 64 + jb*4);
        const float4 BZH = *(const float4*)(sbh + jb*4);
        const float4 BRH = *(const float4*)(sbh + 32 + jb*4);
        const float4 BHH = *(const float4*)(sbh + 64 + jb*4);
        float* hq = hl + (jb*4)*STRIDE;
        {
            float z = fast_sigmoid(az0 + BZI.x + BZH.x);
            float r = fast_sigmoid(ar0 + BRI.x + BRH.x);
            float c = fast_tanh(ai0 + BHI.x + r * (ah0 + BHH.x));
            float ho = hq[0*STRIDE]; hq[0*STRIDE] = z*ho + (1.f - z)*c;
        }
        {
            float z = fast_sigmoid(az1 + BZI.y + BZH.y);
            float r = fast_sigmoid(ar1 + BRI.y + BRH.y);
            float c = fast_tanh(ai1 + BHI.y + r * (ah1 + BHH.y));
            float ho = hq[1*STRIDE]; hq[1*STRIDE] = z*ho + (1.f - z)*c;
        }
        {
            float z = fast_sigmoid(az2 + BZI.z + BZH.z);
            float r = fast_sigmoid(ar2 + BRI.z + BRH.z);
            float c = fast_tanh(ai2 + BHI.z + r * (ah2 + BHH.z));
            float ho = hq[2*STRIDE]; hq[2*STRIDE] = z*ho + (1.f - z)*c;
        }
        {
            float z = fast_sigmoid(az3 + BZI.w + BZH.w);
            float r = fast_sigmoid(ar3 + BRI.w + BRH.w);
            float c = fast_tanh(ai3 + BHI.w + r * (ah3 + BHH.w));
            float ho = hq[3*STRIDE]; hq[3*STRIDE] = z*ho + (1.f - z)*c;
        }
    }
    #pragma unroll
    for (int j = 0; j < DPDIM; ++j) h[j] = hl[j*STRIDE];
}

// ---------------- init states ----------------
__global__ __launch_bounds__(256) void init_kernel(
    const float* __restrict__ traffic, const float* __restrict__ packets,
    const float* __restrict__ eqlam, const float* __restrict__ avgpkt,
    const float* __restrict__ capacity, const float* __restrict__ queues,
    float* __restrict__ path_state, float* __restrict__ link_state,
    int n_paths, int n_links)
{
    int i = blockIdx.x * 256 + threadIdx.x;
    if (i < n_paths) {
        float4* row = (float4*)(path_state + (size_t)i * DPDIM);
        row[0] = make_float4(traffic[i], packets[i], eqlam[i], avgpkt[i]);
        float4 z = make_float4(0.f, 0.f, 0.f, 0.f);
        #pragma unroll
        for (int k = 1; k < 8; ++k) row[k] = z;
    }
    if (i < n_links) {
        float4* row = (float4*)(link_state + (size_t)i * DPDIM);
        row[0] = make_float4(capacity[i], queues[i], 0.f, 0.f);
        float4 z = make_float4(0.f, 0.f, 0.f, 0.f);
        #pragma unroll
        for (int k = 1; k < 8; ++k) row[k] = z;
    }
}

// ---------------- weight transpose: Up[k][96] -> UpT[jb][k][12] ------------
// UpT[((jb*32)+k)*12 + idx], idx 0..3 = z cols jb*4+c, 4..7 = r, 8..11 = h
__global__ __launch_bounds__(256) void transpose_up_kernel(
    const float* __restrict__ Up, float* __restrict__ UpT)
{
    int i = blockIdx.x * 256 + threadIdx.x;
    if (i >= 8*32*12) return;
    int idx = i % 12;
    int k   = (i / 12) % 32;
    int jb  = i / (12*32);
    int gate = idx >> 2, c = idx & 3;
    UpT[i] = Up[k*GCOLS + gate*32 + jb*4 + c];
}

// ---------------- CSR build ----------------
__global__ __launch_bounds__(256) void zero_counts_kernel(int* __restrict__ counts, int n) {
    int i = blockIdx.x * 256 + threadIdx.x;
    if (i < n) counts[i] = 0;
}
__global__ __launch_bounds__(256) void hist_kernel(
    const int* __restrict__ link_to_path, int* __restrict__ counts, int n) {
    int i = blockIdx.x * 256 + threadIdx.x;
    if (i < n) atomicAdd(&counts[link_to_path[i]], 1);
}
__global__ __launch_bounds__(1024) void scan_kernel(
    const int* __restrict__ counts, int* __restrict__ offsets,
    int* __restrict__ cursor, int n)
{
    __shared__ int s[1024];
    int t = threadIdx.x;
    int chunk = (n + 1023) >> 10;
    int lo = t * chunk;
    int hi = lo + chunk; if (hi > n) hi = n;
    int local = 0;
    for (int i = lo; i < hi; ++i) local += counts[i];
    s[t] = local;
    __syncthreads();
    for (int d = 1; d < 1024; d <<= 1) {
        int v = (t >= d) ? s[t - d] : 0;
        __syncthreads();
        s[t] += v;
        __syncthreads();
    }
    int base = (t > 0) ? s[t - 1] : 0;
    for (int i = lo; i < hi; ++i) {
        offsets[i] = base; cursor[i] = base; base += counts[i];
    }
    if (t == 1023) offsets[n] = s[1023];
}
__global__ __launch_bounds__(256) void fill_kernel(
    const int* __restrict__ link_to_path, int* __restrict__ cursor,
    int* __restrict__ entries, int n) {
    int e = blockIdx.x * 256 + threadIdx.x;
    if (e < n) {
        int l = link_to_path[e];
        int pos = atomicAdd(&cursor[l], 1);
        entries[pos] = e >> 3;   // path id (PLEN == 8)
    }
}

// ---------------- per-link input-gate precompute ---------------------------
// Gi_z = x@Wz + biz + bhz ; Gi_r = x@Wr + bir + bhr ; Gi_h = x@Wh + bih
__global__ __launch_bounds__(128) void gate_pre_kernel(
    const float* __restrict__ link_state,
    const float* __restrict__ Wp, const float* __restrict__ bip,
    const float* __restrict__ bhp,
    float* __restrict__ Gi, int* __restrict__ nzf, int n_links)
{
    __shared__ __align__(16) float sW[DPDIM*GCOLS];
    __shared__ __align__(16) float sbi[GCOLS];
    __shared__ __align__(16) float sbh[GCOLS];
    int t = threadIdx.x;
    for (int i = t; i < DPDIM*GCOLS; i += 128) sW[i] = Wp[i];
    if (t < GCOLS) { sbi[t] = bip[t]; sbh[t] = bhp[t]; }
    __syncthreads();
    int l = blockIdx.x * 128 + t;
    if (l >= n_links) return;
    float x[DPDIM];
    bool nz = false;
    const float4* row = (const float4*)(link_state + (size_t)l * DPDIM);
    #pragma unroll
    for (int k = 0; k < 8; ++k) {
        float4 v = row[k];
        x[4*k+0]=v.x; x[4*k+1]=v.y; x[4*k+2]=v.z; x[4*k+3]=v.w;
        nz = nz || (v.x != 0.f) || (v.y != 0.f) || (v.z != 0.f) || (v.w != 0.f);
    }
    float* G = Gi + (size_t)l * GCOLS;
    #pragma unroll 1
    for (int jb = 0; jb < 8; ++jb) {
        float4 az = {0,0,0,0}, ar = {0,0,0,0}, ah = {0,0,0,0};
        const float* wp = sW + jb*4;
        #pragma unroll
        for (int k = 0; k < DPDIM; ++k) {
            const float xk = x[k];
            const float4 WZ = *(const float4*)(wp + k*GCOLS);
            const float4 WR = *(const float4*)(wp + k*GCOLS + 32);
            const float4 WH = *(const float4*)(wp + k*GCOLS + 64);
            ACC4F(az, xk, WZ); ACC4F(ar, xk, WR); ACC4F(ah, xk, WH);
        }
        const float4 bz = *(const float4*)(sbi + jb*4);
        const float4 br = *(const float4*)(sbi + 32 + jb*4);
        const float4 bh = *(const float4*)(sbi + 64 + jb*4);
        const float4 cz = *(const float4*)(sbh + jb*4);
        const float4 cr = *(const float4*)(sbh + 32 + jb*4);
        *(float4*)(G + jb*4)      = make_float4(az.x+bz.x+cz.x, az.y+bz.y+cz.y,
                                                az.z+bz.z+cz.z, az.w+bz.w+cz.w);
        *(float4*)(G + 32 + jb*4) = make_float4(ar.x+br.x+cr.x, ar.y+br.y+cr.y,
                                                ar.z+br.z+cr.z, ar.w+br.w+cr.w);
        *(float4*)(G + 64 + jb*4) = make_float4(ah.x+bh.x, ah.y+bh.y, ah.z+bh.z, ah.w+bh.w);
    }
    nzf[l] = nz ? 1 : 0;
}

// ---------------- path GRU ---------------------------------------------------
// Round-0 structure (h in LDS double-buffer, jb loop #pragma unroll 1) with
// ONE change: h is read from LDS into registers ONCE per step (batched 32
// ds_read, single wait, statically indexed via full k-unroll) instead of
// being re-read inside every jb (256 latency-chained ds_read/step). The
// `ho` epilogue value stays an LDS read to keep all register indices static
// under the runtime jb loop (rule #20). Next-step link id is prefetched.
__global__ __launch_bounds__(64, 1) void path_kernel(
    const float* __restrict__ Gi, const int* __restrict__ nzf,
    float* __restrict__ path_state, const int* __restrict__ link_to_path,
    const float* __restrict__ UpT, const float* __restrict__ bhp, int n_paths)
{
    __shared__ float hbuf[2*DPDIM*64];    // 16 KB, [buf][k][lane]
    int t = threadIdx.x;
    int p = blockIdx.x * 64 + t;
    bool act = p < n_paths;
    int pp = act ? p : (n_paths - 1);
    {
        const float4* row = (const float4*)(path_state + (size_t)pp * DPDIM);
        #pragma unroll
        for (int k4 = 0; k4 < 8; ++k4) {
            float4 v = row[k4];
            hbuf[(4*k4+0)*64 + t] = v.x; hbuf[(4*k4+1)*64 + t] = v.y;
            hbuf[(4*k4+2)*64 + t] = v.z; hbuf[(4*k4+3)*64 + t] = v.w;
        }
    }
    int cur = 0;
    int lcur = link_to_path[pp*PLEN];
    #pragma unroll 1
    for (int s = 0; s < PLEN; ++s) {
        int lnext = (s < PLEN-1) ? link_to_path[pp*PLEN + s + 1] : lcur;
        bool nz = act && (nzf[lcur] != 0);
        const float* G = Gi + (size_t)lcur * GCOLS;
        const float* hold = hbuf + cur*(DPDIM*64) + t;
        float* hnew = hbuf + (cur^1)*(DPDIM*64) + t;
        // batched h load: one LDS latency exposure per step
        float hreg[DPDIM];
        #pragma unroll
        for (int k = 0; k < DPDIM; ++k) hreg[k] = hold[k*64];
        #pragma unroll 1
        for (int jb = 0; jb < 8; ++jb) {
            float4 az  = *(const float4*)(G + jb*4);
            float4 ar  = *(const float4*)(G + 32 + jb*4);
            float4 gih = *(const float4*)(G + 64 + jb*4);
            float4 ah  = *(const float4*)(bhp + 64 + jb*4);   // uniform
            const float* w = UpT + jb*(32*12);
            #pragma unroll
            for (int k = 0; k < DPDIM; ++k) {
                float hk = hreg[k];
                const float4 wz = *(const float4*)(w);
                const float4 wr = *(const float4*)(w + 4);
                const float4 wh = *(const float4*)(w + 8);
                ACC4F(az, hk, wz); ACC4F(ar, hk, wr); ACC4F(ah, hk, wh);
                w += 12;
            }
#define PWC(C, j) { \
            float zz = fast_sigmoid(az.C); \
            float rr = fast_sigmoid(ar.C); \
            float cc = fast_tanh(gih.C + rr * ah.C); \
            float ho = hold[(jb*4+j)*64]; \
            hnew[(jb*4+j)*64] = nz ? (cc + zz * (ho - cc)) : ho; }
            PWC(x, 0) PWC(y, 1) PWC(z, 2) PWC(w, 3)
#undef PWC
        }
        cur ^= 1;
        lcur = lnext;
    }
    if (act) {
        const float* hf = hbuf + cur*(DPDIM*64) + t;
        float4* row = (float4*)(path_state + (size_t)p * DPDIM);
        #pragma unroll
        for (int k4 = 0; k4 < 8; ++k4)
            row[k4] = make_float4(hf[(4*k4+0)*64], hf[(4*k4+1)*64],
                                  hf[(4*k4+2)*64], hf[(4*k4+3)*64]);
    }
}

// ---------------- segment sum: path states -> per-link sums ----------------
__global__ __launch_bounds__(256) void seg_sum_kernel(
    const float* __restrict__ path_state, const int* __restrict__ offsets,
    const int* __restrict__ entries, float* __restrict__ path_sum, int n_links)
{
    int t = threadIdx.x;
    int d = t & 31, li = t >> 5;        // 8 links per block, 32 dims each
    int l = blockIdx.x * 8 + li;
    if (l >= n_links) return;
    int beg = offsets[l], end = offsets[l+1];
    float a0 = 0.f, a1 = 0.f, a2 = 0.f, a3 = 0.f;
    int q = beg;
    for (; q + 3 < end; q += 4) {
        int p0 = entries[q], p1 = entries[q+1], p2 = entries[q+2], p3 = entries[q+3];
        a0 += path_state[(size_t)p0 * DPDIM + d];
        a1 += path_state[(size_t)p1 * DPDIM + d];
        a2 += path_state[(size_t)p2 * DPDIM + d];
        a3 += path_state[(size_t)p3 * DPDIM + d];
    }
    for (; q < end; ++q)
        a0 += path_state[(size_t)entries[q] * DPDIM + d];
    path_sum[(size_t)l * DPDIM + d] = (a0 + a1) + (a2 + a3);
}

// ---------------- link GRU: one step, x = path_sum -------------------------
__global__ __launch_bounds__(128, 1) void link_kernel(
    const float* __restrict__ path_sum, float* __restrict__ link_state,
    const float* __restrict__ Wl, const float* __restrict__ Ul,
    const float* __restrict__ bil, const float* __restrict__ bhl, int n_links)
{
    __shared__ __align__(16) float sW[DPDIM*GCOLS];
    __shared__ __align__(16) float sU[DPDIM*GCOLS];
    __shared__ __align__(16) float sbi[GCOLS];
    __shared__ __align__(16) float sbh[GCOLS];
    __shared__ float h_lds[DPDIM * 128];
    int t = threadIdx.x;
    for (int i = t; i < DPDIM*GCOLS; i += 128) { sW[i] = Wl[i]; sU[i] = Ul[i]; }
    for (int i = t; i < GCOLS; i += 128)       { sbi[i] = bil[i]; sbh[i] = bhl[i]; }
    int l = blockIdx.x * 128 + t;
    bool active = l < n_links;
    float h[DPDIM], x[DPDIM];
    if (active) {
        const float4* hrow = (const float4*)(link_state + (size_t)l * DPDIM);
        const float4* xrow = (const float4*)(path_sum + (size_t)l * DPDIM);
        #pragma unroll
        for (int k = 0; k < 8; ++k) {
            float4 v = hrow[k];
            h[4*k+0]=v.x; h[4*k+1]=v.y; h[4*k+2]=v.z; h[4*k+3]=v.w;
            float4 u = xrow[k];
            x[4*k+0]=u.x; x[4*k+1]=u.y; x[4*k+2]=u.z; x[4*k+3]=u.w;
        }
    } else {
        #pragma unroll
        for (int k = 0; k < DPDIM; ++k) { h[k] = 0.f; x[k] = 0.f; }
    }
    #pragma unroll
    for (int j = 0; j < DPDIM; ++j) h_lds[j*128 + t] = h[j];
    __syncthreads();
    if (active) {
        gru_step<128>(h, x, sW, sU, sbi, sbh, &h_lds[t]);
        float4* row = (float4*)(link_state + (size_t)l * DPDIM);
        #pragma unroll
        for (int k = 0; k < 8; ++k)
            row[k] = make_float4(h[4*k+0], h[4*k+1], h[4*k+2], h[4*k+3]);
    }
}

// ---------------- readout: relu(ls@W1+b1) -> relu(@W2+b2) -> @W3+b3 --------
__global__ __launch_bounds__(256) void readout_kernel(
    const float* __restrict__ link_state,
    const float* __restrict__ W1, const float* __restrict__ b1,
    const float* __restrict__ W2, const float* __restrict__ b2,
    const float* __restrict__ W3, const float* __restrict__ b3,
    float* __restrict__ out, int n_links)
{
    __shared__ __align__(16) float s_ls[64*DPDIM];   // 8 KB
    __shared__ float s_m[64*257];                    // 64.25 KB (r1, then r2*w3)
    __shared__ float s_part[256];
    __shared__ float s_w3[RUNITS];
    int t = threadIdx.x;
    int l0 = blockIdx.x * 64;
    int nl = n_links - l0; if (nl > 64) nl = 64;
    for (int i = t; i < nl*DPDIM; i += 256) s_ls[i] = link_state[(size_t)l0*DPDIM + i];
    s_w3[t] = W3[t];
    __syncthreads();
    // r1 = relu(ls @ W1 + b1) ; thread t owns column t
    float w1c[DPDIM];
    #pragma unroll
    for (int k = 0; k < DPDIM; ++k) w1c[k] = W1[k*RUNITS + t];
    float b1t = b1[t];
    for (int i = 0; i < nl; ++i) {
        float a = b1t;
        #pragma unroll
        for (int k = 0; k < DPDIM; ++k) a = fmaf(s_ls[i*DPDIM + k], w1c[k], a);
        s_m[i*257 + t] = fmaxf(a, 0.f);
    }
    __syncthreads();
    // r2 accum: acc[i] = sum_k r1[i][k] * W2[k][t]   (broadcast LDS reads)
    float acc[64];
    #pragma unroll
    for (int i = 0; i < 64; ++i) acc[i] = 0.f;
    for (int k = 0; k < RUNITS; ++k) {
        float w = W2[k*RUNITS + t];
        #pragma unroll
        for (int i = 0; i < 64; ++i) acc[i] = fmaf(s_m[i*257 + k], w, acc[i]);
    }
    __syncthreads();
    // store relu(acc+b2)*w3 back into s_m
    float b2t = b2[t];
    #pragma unroll
    for (int i = 0; i < 64; ++i)
        s_m[i*257 + t] = fmaxf(acc[i] + b2t, 0.f) * s_w3[t];
    __syncthreads();
    // reduce 256 cols per link: thread t handles link i=t>>2, quarter q=t&3
    {
        int i = t >> 2, q = t & 3;
        float ssum = 0.f;
        for (int j = q*64; j < q*64 + 64; ++j) ssum += s_m[i*257 + j];
        s_part[t] = ssum;
    }
    __syncthreads();
    if (t < nl)
        out[l0 + t] = b3[0] + s_part[t*4] + s_part[t*4+1] + s_part[t*4+2] + s_part[t*4+3];
}

// ---------------- launch ----------------
extern "C" void kernel_launch(void* const* d_in, const int* in_sizes, int n_in,
                              void* d_out, int out_size, void* d_ws, size_t ws_size,
                              hipStream_t stream)
{
    const float* traffic  = (const float*)d_in[0];
    const float* packets  = (const float*)d_in[1];
    const float* eqlam    = (const float*)d_in[2];
    const float* avgpkt   = (const float*)d_in[3];
    const float* capacity = (const float*)d_in[4];
    const float* queues   = (const float*)d_in[5];
    const int* link_to_path = (const int*)d_in[6];
    const float* Wp  = (const float*)d_in[13];
    const float* Up  = (const float*)d_in[14];
    const float* bip = (const float*)d_in[15];
    const float* bhp = (const float*)d_in[16];
    const float* Wl  = (const float*)d_in[17];
    const float* Ul  = (const float*)d_in[18];
    const float* bil = (const float*)d_in[19];
    const float* bhl = (const float*)d_in[20];
    const float* W1  = (const float*)d_in[21];
    const float* b1  = (const float*)d_in[22];
    const float* W2  = (const float*)d_in[23];
    const float* b2  = (const float*)d_in[24];
    const float* W3  = (const float*)d_in[25];
    const float* b3  = (const float*)d_in[26];
    const int n_paths = in_sizes[0];     // 100000
    const int n_links = in_sizes[4];     // 20000
    const int n_ent   = in_sizes[6];     // 800000

    char* ws = (char*)d_ws;
    size_t off = 0;
    auto salloc = [&](size_t bytes) -> void* {
        void* p = ws + off;
        off += (bytes + 255) & ~size_t(255);
        return p;
    };
    float* path_state = (float*)salloc((size_t)n_paths * DPDIM * 4);
    float* link_state = (float*)salloc((size_t)n_links * DPDIM * 4);
    float* Gi         = (float*)salloc((size_t)n_links * GCOLS * 4);
    float* path_sum   = Gi;
    float* UpT    = (float*)salloc((size_t)8 * 32 * 12 * 4);
    int* nzf     = (int*)salloc((size_t)n_links * 4);
    int* counts  = (int*)salloc((size_t)n_links * 4);
    int* offsets = (int*)salloc((size_t)(n_links + 1) * 4);
    int* cursor  = (int*)salloc((size_t)n_links * 4);
    int* entries = (int*)salloc((size_t)n_ent * 4);
    (void)ws_size; (void)n_in; (void)out_size;

    int gmax = ( (n_paths > n_links ? n_paths : n_links) + 255 ) / 256;
    zero_counts_kernel<<<(n_links + 255)/256, 256, 0, stream>>>(counts, n_links);
    init_kernel<<<gmax, 256, 0, stream>>>(traffic, packets, eqlam, avgpkt,
                                          capacity, queues, path_state, link_state,
                                          n_paths, n_links);
    transpose_up_kernel<<<(8*32*12 + 255)/256, 256, 0, stream>>>(Up, UpT);
    hist_kernel<<<(n_ent + 255)/256, 256, 0, stream>>>(link_to_path, counts, n_ent);
    scan_kernel<<<1, 1024, 0, stream>>>(counts, offsets, cursor, n_links);
    fill_kernel<<<(n_ent + 255)/256, 256, 0, stream>>>(link_to_path, cursor, entries, n_ent);

    for (int it = 0; it < T_ITERS; ++it) {
        gate_pre_kernel<<<(n_links + 127)/128, 128, 0, stream>>>(
            link_state, Wp, bip, bhp, Gi, nzf, n_links);
        path_kernel<<<(n_paths + 63)/64, 64, 0, stream>>>(
            Gi, nzf, path_state, link_to_path, UpT, bhp, n_paths);
        seg_sum_kernel<<<(n_links + 7)/8, 256, 0, stream>>>(
            path_state, offsets, entries, path_sum, n_links);
        link_kernel<<<(n_links + 127)/128, 128, 0, stream>>>(
            path_sum, link_state, Wl, Ul, bil, bhl, n_links);
    }
    readout_kernel<<<(n_links + 63)/64, 256, 0, stream>>>(
        link_state, W1, b1, W2, b2, W3, b3, (float*)d_out, n_links);
}

// Round 3
// 1580.008 us; speedup vs baseline: 2.2502x; 1.4268x over previous
//
#include <hip/hip_runtime.h>

#define DPDIM 32         // path/link state dim
#define GCOLS 96         // 3*DPDIM gate columns
#define PLEN 8
#define T_ITERS 8
#define RUNITS 256

// ---------------- fast activations (v_exp_f32 + v_rcp_f32) ----------------
__device__ __forceinline__ float fast_sigmoid(float a) {
    return __builtin_amdgcn_rcpf(1.0f + __expf(-a));
}
__device__ __forceinline__ float fast_tanh(float a) {
    // tanh(x) = 1 - 2/(1+e^{2x}); stable at both infinities
    return 1.0f - 2.0f * __builtin_amdgcn_rcpf(1.0f + __expf(2.0f * a));
}

#define ACC4(a0,a1,a2,a3, s, V) \
    a0 = fmaf((s), (V).x, a0); a1 = fmaf((s), (V).y, a1); \
    a2 = fmaf((s), (V).z, a2); a3 = fmaf((s), (V).w, a3);

#define ACC4F(A, s, V) \
    A.x = fmaf((s), (V).x, A.x); A.y = fmaf((s), (V).y, A.y); \
    A.z = fmaf((s), (V).z, A.z); A.w = fmaf((s), (V).w, A.w);

// ---------------- full GRU step (used by link_kernel only) ----------------
template<int STRIDE>
__device__ __forceinline__ void gru_step(
    float* __restrict__ h, const float* __restrict__ x,
    const float* __restrict__ sW, const float* __restrict__ sU,
    const float* __restrict__ sbi, const float* __restrict__ sbh,
    float* __restrict__ hl)
{
    for (int jb = 0; jb < 8; ++jb) {
        float az0=0.f,az1=0.f,az2=0.f,az3=0.f;
        float ar0=0.f,ar1=0.f,ar2=0.f,ar3=0.f;
        float ai0=0.f,ai1=0.f,ai2=0.f,ai3=0.f;
        float ah0=0.f,ah1=0.f,ah2=0.f,ah3=0.f;
        const float* wp = sW + jb*4;
        const float* up = sU + jb*4;
        #pragma unroll
        for (int k = 0; k < DPDIM; ++k) {
            const float xk = x[k], hk = h[k];
            const float4 WZ = *(const float4*)(wp + k*GCOLS);
            const float4 WR = *(const float4*)(wp + k*GCOLS + 32);
            const float4 WH = *(const float4*)(wp + k*GCOLS + 64);
            const float4 UZ = *(const float4*)(up + k*GCOLS);
            const float4 UR = *(const float4*)(up + k*GCOLS + 32);
            const float4 UH = *(const float4*)(up + k*GCOLS + 64);
            ACC4(az0,az1,az2,az3, xk, WZ); ACC4(az0,az1,az2,az3, hk, UZ);
            ACC4(ar0,ar1,ar2,ar3, xk, WR); ACC4(ar0,ar1,ar2,ar3, hk, UR);
            ACC4(ai0,ai1,ai2,ai3, xk, WH);
            ACC4(ah0,ah1,ah2,ah3, hk, UH);
        }
        const float4 BZI = *(const float4*)(sbi + jb*4);
        const float4 BRI = *(const float4*)(sbi + 32 + jb*4);
        const float4 BHI = *(const float4*)(sbi + 64 + jb*4);
        const float4 BZH = *(const float4*)(sbh + jb*4);
        const float4 BRH = *(const float4*)(sbh + 32 + jb*4);
        const float4 BHH = *(const float4*)(sbh + 64 + jb*4);
        float* hq = hl + (jb*4)*STRIDE;
        {
            float z = fast_sigmoid(az0 + BZI.x + BZH.x);
            float r = fast_sigmoid(ar0 + BRI.x + BRH.x);
            float c = fast_tanh(ai0 + BHI.x + r * (ah0 + BHH.x));
            float ho = hq[0*STRIDE]; hq[0*STRIDE] = z*ho + (1.f - z)*c;
        }
        {
            float z = fast_sigmoid(az1 + BZI.y + BZH.y);
            float r = fast_sigmoid(ar1 + BRI.y + BRH.y);
            float c = fast_tanh(ai1 + BHI.y + r * (ah1 + BHH.y));
            float ho = hq[1*STRIDE]; hq[1*STRIDE] = z*ho + (1.f - z)*c;
        }
        {
            float z = fast_sigmoid(az2 + BZI.z + BZH.z);
            float r = fast_sigmoid(ar2 + BRI.z + BRH.z);
            float c = fast_tanh(ai2 + BHI.z + r * (ah2 + BHH.z));
            float ho = hq[2*STRIDE]; hq[2*STRIDE] = z*ho + (1.f - z)*c;
        }
        {
            float z = fast_sigmoid(az3 + BZI.w + BZH.w);
            float r = fast_sigmoid(ar3 + BRI.w + BRH.w);
            float c = fast_tanh(ai3 + BHI.w + r * (ah3 + BHH.w));
            float ho = hq[3*STRIDE]; hq[3*STRIDE] = z*ho + (1.f - z)*c;
        }
    }
    #pragma unroll
    for (int j = 0; j < DPDIM; ++j) h[j] = hl[j*STRIDE];
}

// ---------------- init states ----------------
__global__ __launch_bounds__(256) void init_kernel(
    const float* __restrict__ traffic, const float* __restrict__ packets,
    const float* __restrict__ eqlam, const float* __restrict__ avgpkt,
    const float* __restrict__ capacity, const float* __restrict__ queues,
    float* __restrict__ path_state, float* __restrict__ link_state,
    int n_paths, int n_links)
{
    int i = blockIdx.x * 256 + threadIdx.x;
    if (i < n_paths) {
        float4* row = (float4*)(path_state + (size_t)i * DPDIM);
        row[0] = make_float4(traffic[i], packets[i], eqlam[i], avgpkt[i]);
        float4 z = make_float4(0.f, 0.f, 0.f, 0.f);
        #pragma unroll
        for (int k = 1; k < 8; ++k) row[k] = z;
    }
    if (i < n_links) {
        float4* row = (float4*)(link_state + (size_t)i * DPDIM);
        row[0] = make_float4(capacity[i], queues[i], 0.f, 0.f);
        float4 z = make_float4(0.f, 0.f, 0.f, 0.f);
        #pragma unroll
        for (int k = 1; k < 8; ++k) row[k] = z;
    }
}

// ---------------- weight transpose: Up[k][96] -> UpT[jb][k][12] ------------
// UpT[((jb*32)+k)*12 + idx], idx 0..3 = z cols jb*4+c, 4..7 = r, 8..11 = h
__global__ __launch_bounds__(256) void transpose_up_kernel(
    const float* __restrict__ Up, float* __restrict__ UpT)
{
    int i = blockIdx.x * 256 + threadIdx.x;
    if (i >= 8*32*12) return;
    int idx = i % 12;
    int k   = (i / 12) % 32;
    int jb  = i / (12*32);
    int gate = idx >> 2, c = idx & 3;
    UpT[i] = Up[k*GCOLS + gate*32 + jb*4 + c];
}

// ---------------- CSR build ----------------
__global__ __launch_bounds__(256) void zero_counts_kernel(int* __restrict__ counts, int n) {
    int i = blockIdx.x * 256 + threadIdx.x;
    if (i < n) counts[i] = 0;
}
__global__ __launch_bounds__(256) void hist_kernel(
    const int* __restrict__ link_to_path, int* __restrict__ counts, int n) {
    int i = blockIdx.x * 256 + threadIdx.x;
    if (i < n) atomicAdd(&counts[link_to_path[i]], 1);
}
__global__ __launch_bounds__(1024) void scan_kernel(
    const int* __restrict__ counts, int* __restrict__ offsets,
    int* __restrict__ cursor, int n)
{
    __shared__ int s[1024];
    int t = threadIdx.x;
    int chunk = (n + 1023) >> 10;
    int lo = t * chunk;
    int hi = lo + chunk; if (hi > n) hi = n;
    int local = 0;
    for (int i = lo; i < hi; ++i) local += counts[i];
    s[t] = local;
    __syncthreads();
    for (int d = 1; d < 1024; d <<= 1) {
        int v = (t >= d) ? s[t - d] : 0;
        __syncthreads();
        s[t] += v;
        __syncthreads();
    }
    int base = (t > 0) ? s[t - 1] : 0;
    for (int i = lo; i < hi; ++i) {
        offsets[i] = base; cursor[i] = base; base += counts[i];
    }
    if (t == 1023) offsets[n] = s[1023];
}
__global__ __launch_bounds__(256) void fill_kernel(
    const int* __restrict__ link_to_path, int* __restrict__ cursor,
    int* __restrict__ entries, int n) {
    int e = blockIdx.x * 256 + threadIdx.x;
    if (e < n) {
        int l = link_to_path[e];
        int pos = atomicAdd(&cursor[l], 1);
        entries[pos] = e >> 3;   // path id (PLEN == 8)
    }
}

// ---------------- per-link input-gate precompute ---------------------------
// Gi_z = x@Wz + biz + bhz ; Gi_r = x@Wr + bir + bhr ; Gi_h = x@Wh + bih
__global__ __launch_bounds__(128) void gate_pre_kernel(
    const float* __restrict__ link_state,
    const float* __restrict__ Wp, const float* __restrict__ bip,
    const float* __restrict__ bhp,
    float* __restrict__ Gi, int* __restrict__ nzf, int n_links)
{
    __shared__ __align__(16) float sW[DPDIM*GCOLS];
    __shared__ __align__(16) float sbi[GCOLS];
    __shared__ __align__(16) float sbh[GCOLS];
    int t = threadIdx.x;
    for (int i = t; i < DPDIM*GCOLS; i += 128) sW[i] = Wp[i];
    if (t < GCOLS) { sbi[t] = bip[t]; sbh[t] = bhp[t]; }
    __syncthreads();
    int l = blockIdx.x * 128 + t;
    if (l >= n_links) return;
    float x[DPDIM];
    bool nz = false;
    const float4* row = (const float4*)(link_state + (size_t)l * DPDIM);
    #pragma unroll
    for (int k = 0; k < 8; ++k) {
        float4 v = row[k];
        x[4*k+0]=v.x; x[4*k+1]=v.y; x[4*k+2]=v.z; x[4*k+3]=v.w;
        nz = nz || (v.x != 0.f) || (v.y != 0.f) || (v.z != 0.f) || (v.w != 0.f);
    }
    float* G = Gi + (size_t)l * GCOLS;
    #pragma unroll 1
    for (int jb = 0; jb < 8; ++jb) {
        float4 az = {0,0,0,0}, ar = {0,0,0,0}, ah = {0,0,0,0};
        const float* wp = sW + jb*4;
        #pragma unroll
        for (int k = 0; k < DPDIM; ++k) {
            const float xk = x[k];
            const float4 WZ = *(const float4*)(wp + k*GCOLS);
            const float4 WR = *(const float4*)(wp + k*GCOLS + 32);
            const float4 WH = *(const float4*)(wp + k*GCOLS + 64);
            ACC4F(az, xk, WZ); ACC4F(ar, xk, WR); ACC4F(ah, xk, WH);
        }
        const float4 bz = *(const float4*)(sbi + jb*4);
        const float4 br = *(const float4*)(sbi + 32 + jb*4);
        const float4 bh = *(const float4*)(sbi + 64 + jb*4);
        const float4 cz = *(const float4*)(sbh + jb*4);
        const float4 cr = *(const float4*)(sbh + 32 + jb*4);
        *(float4*)(G + jb*4)      = make_float4(az.x+bz.x+cz.x, az.y+bz.y+cz.y,
                                                az.z+bz.z+cz.z, az.w+bz.w+cz.w);
        *(float4*)(G + 32 + jb*4) = make_float4(ar.x+br.x+cr.x, ar.y+br.y+cr.y,
                                                ar.z+br.z+cr.z, ar.w+br.w+cr.w);
        *(float4*)(G + 64 + jb*4) = make_float4(ah.x+bh.x, ah.y+bh.y, ah.z+bh.z, ah.w+bh.w);
    }
    nzf[l] = nz ? 1 : 0;
}

// ---------------- path GRU: 4 waves per block, column-split ----------------
// 64 paths per 256-thread block. Wave eps (= t>>6) computes gate-column
// blocks jb in {2*eps, 2*eps+1} (i.e. h columns [eps*8, eps*8+8)) for all
// 64 paths. Weights stay wave-uniform (jb derived via readfirstlane ->
// provably scalar -> s_load broadcast). h lives in the round-0 [col][lane]
// LDS double buffer; waves exchange halves with ONE __syncthreads per step.
// Inner loop is round-0's proven body (unroll-4 k loop, h read from LDS).
// Wave count: 1563 -> 6252 (~6 waves/SIMD) to hide s_load/global latency.
__global__ __launch_bounds__(256, 1) void path_kernel(
    const float* __restrict__ Gi, const int* __restrict__ nzf,
    float* __restrict__ path_state, const int* __restrict__ link_to_path,
    const float* __restrict__ UpT, const float* __restrict__ bhp, int n_paths)
{
    __shared__ float hbuf[2*DPDIM*64];    // 16 KB, [buf][col][pathlane]
    int t = threadIdx.x;
    int pe = t & 63;                       // path lane within block
    int eps = __builtin_amdgcn_readfirstlane(t >> 6);   // wave id, scalar
    int p = blockIdx.x * 64 + pe;
    bool act = p < n_paths;
    int pp = act ? p : (n_paths - 1);

    // init: wave eps loads its own 8 columns of its path's state
    {
        const float4* row = (const float4*)(path_state + (size_t)pp * DPDIM + eps*8);
        float4 v0 = row[0], v1 = row[1];
        int c0 = eps*8;
        hbuf[(c0+0)*64 + pe] = v0.x; hbuf[(c0+1)*64 + pe] = v0.y;
        hbuf[(c0+2)*64 + pe] = v0.z; hbuf[(c0+3)*64 + pe] = v0.w;
        hbuf[(c0+4)*64 + pe] = v1.x; hbuf[(c0+5)*64 + pe] = v1.y;
        hbuf[(c0+6)*64 + pe] = v1.z; hbuf[(c0+7)*64 + pe] = v1.w;
    }
    __syncthreads();

    int cur = 0;
    int jb0 = eps*2;
    #pragma unroll 1
    for (int s = 0; s < PLEN; ++s) {
        int l = link_to_path[pp*PLEN + s];
        bool nz = act && (nzf[l] != 0);
        const float* G = Gi + (size_t)l * GCOLS;
        const float* hold = hbuf + cur*(DPDIM*64) + pe;
        float* hnew = hbuf + (cur^1)*(DPDIM*64) + pe;
        #pragma unroll 1
        for (int jj = 0; jj < 2; ++jj) {
            int jb = jb0 + jj;                               // wave-uniform
            float4 az  = *(const float4*)(G + jb*4);
            float4 ar  = *(const float4*)(G + 32 + jb*4);
            float4 gih = *(const float4*)(G + 64 + jb*4);
            float4 ah  = *(const float4*)(bhp + 64 + jb*4);  // uniform s_load
            const float* w = UpT + jb*(32*12);               // uniform s_load
            #pragma unroll 4
            for (int k = 0; k < DPDIM; ++k) {
                float hk = hold[k*64];
                const float4 wz = *(const float4*)(w);
                const float4 wr = *(const float4*)(w + 4);
                const float4 wh = *(const float4*)(w + 8);
                ACC4F(az, hk, wz); ACC4F(ar, hk, wr); ACC4F(ah, hk, wh);
                w += 12;
            }
#define PWC(C, j) { \
            float zz = fast_sigmoid(az.C); \
            float rr = fast_sigmoid(ar.C); \
            float cc = fast_tanh(gih.C + rr * ah.C); \
            float ho = hold[(jb*4+j)*64]; \
            hnew[(jb*4+j)*64] = nz ? (cc + zz * (ho - cc)) : ho; }
            PWC(x, 0) PWC(y, 1) PWC(z, 2) PWC(w, 3)
#undef PWC
        }
        __syncthreads();     // hnew complete + hold reads done across waves
        cur ^= 1;
    }

    if (act) {
        const float* hf = hbuf + cur*(DPDIM*64) + pe;
        int c0 = eps*8;
        float4 a = make_float4(hf[(c0+0)*64], hf[(c0+1)*64],
                               hf[(c0+2)*64], hf[(c0+3)*64]);
        float4 b = make_float4(hf[(c0+4)*64], hf[(c0+5)*64],
                               hf[(c0+6)*64], hf[(c0+7)*64]);
        *(float4*)(path_state + (size_t)p * DPDIM + c0)     = a;
        *(float4*)(path_state + (size_t)p * DPDIM + c0 + 4) = b;
    }
}

// ---------------- segment sum: path states -> per-link sums ----------------
__global__ __launch_bounds__(256) void seg_sum_kernel(
    const float* __restrict__ path_state, const int* __restrict__ offsets,
    const int* __restrict__ entries, float* __restrict__ path_sum, int n_links)
{
    int t = threadIdx.x;
    int d = t & 31, li = t >> 5;        // 8 links per block, 32 dims each
    int l = blockIdx.x * 8 + li;
    if (l >= n_links) return;
    int beg = offsets[l], end = offsets[l+1];
    float a0 = 0.f, a1 = 0.f, a2 = 0.f, a3 = 0.f;
    int q = beg;
    for (; q + 3 < end; q += 4) {
        int p0 = entries[q], p1 = entries[q+1], p2 = entries[q+2], p3 = entries[q+3];
        a0 += path_state[(size_t)p0 * DPDIM + d];
        a1 += path_state[(size_t)p1 * DPDIM + d];
        a2 += path_state[(size_t)p2 * DPDIM + d];
        a3 += path_state[(size_t)p3 * DPDIM + d];
    }
    for (; q < end; ++q)
        a0 += path_state[(size_t)entries[q] * DPDIM + d];
    path_sum[(size_t)l * DPDIM + d] = (a0 + a1) + (a2 + a3);
}

// ---------------- link GRU: one step, x = path_sum -------------------------
__global__ __launch_bounds__(128, 1) void link_kernel(
    const float* __restrict__ path_sum, float* __restrict__ link_state,
    const float* __restrict__ Wl, const float* __restrict__ Ul,
    const float* __restrict__ bil, const float* __restrict__ bhl, int n_links)
{
    __shared__ __align__(16) float sW[DPDIM*GCOLS];
    __shared__ __align__(16) float sU[DPDIM*GCOLS];
    __shared__ __align__(16) float sbi[GCOLS];
    __shared__ __align__(16) float sbh[GCOLS];
    __shared__ float h_lds[DPDIM * 128];
    int t = threadIdx.x;
    for (int i = t; i < DPDIM*GCOLS; i += 128) { sW[i] = Wl[i]; sU[i] = Ul[i]; }
    for (int i = t; i < GCOLS; i += 128)       { sbi[i] = bil[i]; sbh[i] = bhl[i]; }
    int l = blockIdx.x * 128 + t;
    bool active = l < n_links;
    float h[DPDIM], x[DPDIM];
    if (active) {
        const float4* hrow = (const float4*)(link_state + (size_t)l * DPDIM);
        const float4* xrow = (const float4*)(path_sum + (size_t)l * DPDIM);
        #pragma unroll
        for (int k = 0; k < 8; ++k) {
            float4 v = hrow[k];
            h[4*k+0]=v.x; h[4*k+1]=v.y; h[4*k+2]=v.z; h[4*k+3]=v.w;
            float4 u = xrow[k];
            x[4*k+0]=u.x; x[4*k+1]=u.y; x[4*k+2]=u.z; x[4*k+3]=u.w;
        }
    } else {
        #pragma unroll
        for (int k = 0; k < DPDIM; ++k) { h[k] = 0.f; x[k] = 0.f; }
    }
    #pragma unroll
    for (int j = 0; j < DPDIM; ++j) h_lds[j*128 + t] = h[j];
    __syncthreads();
    if (active) {
        gru_step<128>(h, x, sW, sU, sbi, sbh, &h_lds[t]);
        float4* row = (float4*)(link_state + (size_t)l * DPDIM);
        #pragma unroll
        for (int k = 0; k < 8; ++k)
            row[k] = make_float4(h[4*k+0], h[4*k+1], h[4*k+2], h[4*k+3]);
    }
}

// ---------------- readout: relu(ls@W1+b1) -> relu(@W2+b2) -> @W3+b3 --------
__global__ __launch_bounds__(256) void readout_kernel(
    const float* __restrict__ link_state,
    const float* __restrict__ W1, const float* __restrict__ b1,
    const float* __restrict__ W2, const float* __restrict__ b2,
    const float* __restrict__ W3, const float* __restrict__ b3,
    float* __restrict__ out, int n_links)
{
    __shared__ __align__(16) float s_ls[64*DPDIM];   // 8 KB
    __shared__ float s_m[64*257];                    // 64.25 KB (r1, then r2*w3)
    __shared__ float s_part[256];
    __shared__ float s_w3[RUNITS];
    int t = threadIdx.x;
    int l0 = blockIdx.x * 64;
    int nl = n_links - l0; if (nl > 64) nl = 64;
    for (int i = t; i < nl*DPDIM; i += 256) s_ls[i] = link_state[(size_t)l0*DPDIM + i];
    s_w3[t] = W3[t];
    __syncthreads();
    // r1 = relu(ls @ W1 + b1) ; thread t owns column t
    float w1c[DPDIM];
    #pragma unroll
    for (int k = 0; k < DPDIM; ++k) w1c[k] = W1[k*RUNITS + t];
    float b1t = b1[t];
    for (int i = 0; i < nl; ++i) {
        float a = b1t;
        #pragma unroll
        for (int k = 0; k < DPDIM; ++k) a = fmaf(s_ls[i*DPDIM + k], w1c[k], a);
        s_m[i*257 + t] = fmaxf(a, 0.f);
    }
    __syncthreads();
    // r2 accum: acc[i] = sum_k r1[i][k] * W2[k][t]   (broadcast LDS reads)
    float acc[64];
    #pragma unroll
    for (int i = 0; i < 64; ++i) acc[i] = 0.f;
    for (int k = 0; k < RUNITS; ++k) {
        float w = W2[k*RUNITS + t];
        #pragma unroll
        for (int i = 0; i < 64; ++i) acc[i] = fmaf(s_m[i*257 + k], w, acc[i]);
    }
    __syncthreads();
    // store relu(acc+b2)*w3 back into s_m
    float b2t = b2[t];
    #pragma unroll
    for (int i = 0; i < 64; ++i)
        s_m[i*257 + t] = fmaxf(acc[i] + b2t, 0.f) * s_w3[t];
    __syncthreads();
    // reduce 256 cols per link: thread t handles link i=t>>2, quarter q=t&3
    {
        int i = t >> 2, q = t & 3;
        float ssum = 0.f;
        for (int j = q*64; j < q*64 + 64; ++j) ssum += s_m[i*257 + j];
        s_part[t] = ssum;
    }
    __syncthreads();
    if (t < nl)
        out[l0 + t] = b3[0] + s_part[t*4] + s_part[t*4+1] + s_part[t*4+2] + s_part[t*4+3];
}

// ---------------- launch ----------------
extern "C" void kernel_launch(void* const* d_in, const int* in_sizes, int n_in,
                              void* d_out, int out_size, void* d_ws, size_t ws_size,
                              hipStream_t stream)
{
    const float* traffic  = (const float*)d_in[0];
    const float* packets  = (const float*)d_in[1];
    const float* eqlam    = (const float*)d_in[2];
    const float* avgpkt   = (const float*)d_in[3];
    const float* capacity = (const float*)d_in[4];
    const float* queues   = (const float*)d_in[5];
    const int* link_to_path = (const int*)d_in[6];
    const float* Wp  = (const float*)d_in[13];
    const float* Up  = (const float*)d_in[14];
    const float* bip = (const float*)d_in[15];
    const float* bhp = (const float*)d_in[16];
    const float* Wl  = (const float*)d_in[17];
    const float* Ul  = (const float*)d_in[18];
    const float* bil = (const float*)d_in[19];
    const float* bhl = (const float*)d_in[20];
    const float* W1  = (const float*)d_in[21];
    const float* b1  = (const float*)d_in[22];
    const float* W2  = (const float*)d_in[23];
    const float* b2  = (const float*)d_in[24];
    const float* W3  = (const float*)d_in[25];
    const float* b3  = (const float*)d_in[26];
    const int n_paths = in_sizes[0];     // 100000
    const int n_links = in_sizes[4];     // 20000
    const int n_ent   = in_sizes[6];     // 800000

    char* ws = (char*)d_ws;
    size_t off = 0;
    auto salloc = [&](size_t bytes) -> void* {
        void* p = ws + off;
        off += (bytes + 255) & ~size_t(255);
        return p;
    };
    float* path_state = (float*)salloc((size_t)n_paths * DPDIM * 4);
    float* link_state = (float*)salloc((size_t)n_links * DPDIM * 4);
    float* Gi         = (float*)salloc((size_t)n_links * GCOLS * 4);
    float* path_sum   = Gi;
    float* UpT    = (float*)salloc((size_t)8 * 32 * 12 * 4);
    int* nzf     = (int*)salloc((size_t)n_links * 4);
    int* counts  = (int*)salloc((size_t)n_links * 4);
    int* offsets = (int*)salloc((size_t)(n_links + 1) * 4);
    int* cursor  = (int*)salloc((size_t)n_links * 4);
    int* entries = (int*)salloc((size_t)n_ent * 4);
    (void)ws_size; (void)n_in; (void)out_size;

    int gmax = ( (n_paths > n_links ? n_paths : n_links) + 255 ) / 256;
    zero_counts_kernel<<<(n_links + 255)/256, 256, 0, stream>>>(counts, n_links);
    init_kernel<<<gmax, 256, 0, stream>>>(traffic, packets, eqlam, avgpkt,
                                          capacity, queues, path_state, link_state,
                                          n_paths, n_links);
    transpose_up_kernel<<<(8*32*12 + 255)/256, 256, 0, stream>>>(Up, UpT);
    hist_kernel<<<(n_ent + 255)/256, 256, 0, stream>>>(link_to_path, counts, n_ent);
    scan_kernel<<<1, 1024, 0, stream>>>(counts, offsets, cursor, n_links);
    fill_kernel<<<(n_ent + 255)/256, 256, 0, stream>>>(link_to_path, cursor, entries, n_ent);

    for (int it = 0; it < T_ITERS; ++it) {
        gate_pre_kernel<<<(n_links + 127)/128, 128, 0, stream>>>(
            link_state, Wp, bip, bhp, Gi, nzf, n_links);
        path_kernel<<<(n_paths + 63)/64, 256, 0, stream>>>(
            Gi, nzf, path_state, link_to_path, UpT, bhp, n_paths);
        seg_sum_kernel<<<(n_links + 7)/8, 256, 0, stream>>>(
            path_state, offsets, entries, path_sum, n_links);
        link_kernel<<<(n_links + 127)/128, 128, 0, stream>>>(
            path_sum, link_state, Wl, Ul, bil, bhl, n_links);
    }
    readout_kernel<<<(n_links + 63)/64, 256, 0, stream>>>(
        link_state, W1, b1, W2, b2, W3, b3, (float*)d_out, n_links);
}

// Round 4
// 1398.543 us; speedup vs baseline: 2.5422x; 1.1298x over previous
//
#include <hip/hip_runtime.h>

#define DPDIM 32         // path/link state dim
#define GCOLS 96         // 3*DPDIM gate columns
#define PLEN 8
#define T_ITERS 8
#define RUNITS 256

// ---------------- fast activations (v_exp_f32 + v_rcp_f32) ----------------
__device__ __forceinline__ float fast_sigmoid(float a) {
    return __builtin_amdgcn_rcpf(1.0f + __expf(-a));
}
__device__ __forceinline__ float fast_tanh(float a) {
    // tanh(x) = 1 - 2/(1+e^{2x}); stable at both infinities
    return 1.0f - 2.0f * __builtin_amdgcn_rcpf(1.0f + __expf(2.0f * a));
}

#define ACC4F(A, s, V) \
    A.x = fmaf((s), (V).x, A.x); A.y = fmaf((s), (V).y, A.y); \
    A.z = fmaf((s), (V).z, A.z); A.w = fmaf((s), (V).w, A.w);

// ---------------- init states ----------------
__global__ __launch_bounds__(256) void init_kernel(
    const float* __restrict__ traffic, const float* __restrict__ packets,
    const float* __restrict__ eqlam, const float* __restrict__ avgpkt,
    const float* __restrict__ capacity, const float* __restrict__ queues,
    float* __restrict__ path_state, float* __restrict__ link_state,
    int n_paths, int n_links)
{
    int i = blockIdx.x * 256 + threadIdx.x;
    if (i < n_paths) {
        float4* row = (float4*)(path_state + (size_t)i * DPDIM);
        row[0] = make_float4(traffic[i], packets[i], eqlam[i], avgpkt[i]);
        float4 z = make_float4(0.f, 0.f, 0.f, 0.f);
        #pragma unroll
        for (int k = 1; k < 8; ++k) row[k] = z;
    }
    if (i < n_links) {
        float4* row = (float4*)(link_state + (size_t)i * DPDIM);
        row[0] = make_float4(capacity[i], queues[i], 0.f, 0.f);
        float4 z = make_float4(0.f, 0.f, 0.f, 0.f);
        #pragma unroll
        for (int k = 1; k < 8; ++k) row[k] = z;
    }
}

// ---------------- weight transpose: W[k][96] -> T[jb][k][12] ---------------
// T[((jb*32)+k)*12 + idx], idx 0..3 = z cols jb*4+c, 4..7 = r, 8..11 = h
__global__ __launch_bounds__(256) void transpose_w_kernel(
    const float* __restrict__ W, float* __restrict__ T)
{
    int i = blockIdx.x * 256 + threadIdx.x;
    if (i >= 8*32*12) return;
    int idx = i % 12;
    int k   = (i / 12) % 32;
    int jb  = i / (12*32);
    int gate = idx >> 2, c = idx & 3;
    T[i] = W[k*GCOLS + gate*32 + jb*4 + c];
}

// ---------------- CSR build ----------------
__global__ __launch_bounds__(256) void zero_counts_kernel(int* __restrict__ counts, int n) {
    int i = blockIdx.x * 256 + threadIdx.x;
    if (i < n) counts[i] = 0;
}
__global__ __launch_bounds__(256) void hist_kernel(
    const int* __restrict__ link_to_path, int* __restrict__ counts, int n) {
    int i = blockIdx.x * 256 + threadIdx.x;
    if (i < n) atomicAdd(&counts[link_to_path[i]], 1);
}
__global__ __launch_bounds__(1024) void scan_kernel(
    const int* __restrict__ counts, int* __restrict__ offsets,
    int* __restrict__ cursor, int n)
{
    __shared__ int s[1024];
    int t = threadIdx.x;
    int chunk = (n + 1023) >> 10;
    int lo = t * chunk;
    int hi = lo + chunk; if (hi > n) hi = n;
    int local = 0;
    for (int i = lo; i < hi; ++i) local += counts[i];
    s[t] = local;
    __syncthreads();
    for (int d = 1; d < 1024; d <<= 1) {
        int v = (t >= d) ? s[t - d] : 0;
        __syncthreads();
        s[t] += v;
        __syncthreads();
    }
    int base = (t > 0) ? s[t - 1] : 0;
    for (int i = lo; i < hi; ++i) {
        offsets[i] = base; cursor[i] = base; base += counts[i];
    }
    if (t == 1023) offsets[n] = s[1023];
}
__global__ __launch_bounds__(256) void fill_kernel(
    const int* __restrict__ link_to_path, int* __restrict__ cursor,
    int* __restrict__ entries, int n) {
    int e = blockIdx.x * 256 + threadIdx.x;
    if (e < n) {
        int l = link_to_path[e];
        int pos = atomicAdd(&cursor[l], 1);
        entries[pos] = e >> 3;   // path id (PLEN == 8)
    }
}

// ---------------- per-link input-gate precompute (column-split) ------------
// 64 links/block, 256 threads = 4 waves; wave eps computes jb {2eps,2eps+1}.
// x lives in registers (loaded from global); weights via WpT scalar loads.
// Accumulation order per column: k ascending, x only -> bit-identical to
// the previous gate_pre.
__global__ __launch_bounds__(256, 1) void gate_pre_kernel(
    const float* __restrict__ link_state,
    const float* __restrict__ WpT, const float* __restrict__ bip,
    const float* __restrict__ bhp,
    float* __restrict__ Gi, int* __restrict__ nzf, int n_links)
{
    int t = threadIdx.x;
    int pe = t & 63;
    int eps = __builtin_amdgcn_readfirstlane(t >> 6);
    int l = blockIdx.x * 64 + pe;
    bool act = l < n_links;
    int ll = act ? l : (n_links - 1);

    float x[DPDIM];
    bool nz = false;
    {
        const float4* row = (const float4*)(link_state + (size_t)ll * DPDIM);
        #pragma unroll
        for (int k4 = 0; k4 < 8; ++k4) {
            float4 v = row[k4];
            x[4*k4+0]=v.x; x[4*k4+1]=v.y; x[4*k4+2]=v.z; x[4*k4+3]=v.w;
            nz = nz || (v.x != 0.f) || (v.y != 0.f) || (v.z != 0.f) || (v.w != 0.f);
        }
    }
    float* G = Gi + (size_t)ll * GCOLS;
    int jb0 = eps*2;
    #pragma unroll 1
    for (int jj = 0; jj < 2; ++jj) {
        int jb = jb0 + jj;                              // wave-uniform
        float4 az = {0,0,0,0}, ar = {0,0,0,0}, ah = {0,0,0,0};
        const float* w = WpT + jb*(32*12);              // uniform s_load base
        #pragma unroll 4
        for (int k = 0; k < DPDIM; ++k) {
            float xk = x[k];
            const float4 wz = *(const float4*)(w);
            const float4 wr = *(const float4*)(w + 4);
            const float4 wh = *(const float4*)(w + 8);
            ACC4F(az, xk, wz); ACC4F(ar, xk, wr); ACC4F(ah, xk, wh);
            w += 12;
        }
        const float4 bz = *(const float4*)(bip + jb*4);
        const float4 br = *(const float4*)(bip + 32 + jb*4);
        const float4 bh = *(const float4*)(bip + 64 + jb*4);
        const float4 cz = *(const float4*)(bhp + jb*4);
        const float4 cr = *(const float4*)(bhp + 32 + jb*4);
        if (act) {
            *(float4*)(G + jb*4)      = make_float4(az.x+bz.x+cz.x, az.y+bz.y+cz.y,
                                                    az.z+bz.z+cz.z, az.w+bz.w+cz.w);
            *(float4*)(G + 32 + jb*4) = make_float4(ar.x+br.x+cr.x, ar.y+br.y+cr.y,
                                                    ar.z+br.z+cr.z, ar.w+br.w+cr.w);
            *(float4*)(G + 64 + jb*4) = make_float4(ah.x+bh.x, ah.y+bh.y,
                                                    ah.z+bh.z, ah.w+bh.w);
        }
    }
    if (act && eps == 0) nzf[l] = nz ? 1 : 0;
}

// ---------------- path GRU: 4 waves per block, column-split ----------------
// (round-3 winner, unchanged)
__global__ __launch_bounds__(256, 1) void path_kernel(
    const float* __restrict__ Gi, const int* __restrict__ nzf,
    float* __restrict__ path_state, const int* __restrict__ link_to_path,
    const float* __restrict__ UpT, const float* __restrict__ bhp, int n_paths)
{
    __shared__ float hbuf[2*DPDIM*64];    // 16 KB, [buf][col][pathlane]
    int t = threadIdx.x;
    int pe = t & 63;                       // path lane within block
    int eps = __builtin_amdgcn_readfirstlane(t >> 6);   // wave id, scalar
    int p = blockIdx.x * 64 + pe;
    bool act = p < n_paths;
    int pp = act ? p : (n_paths - 1);

    {
        const float4* row = (const float4*)(path_state + (size_t)pp * DPDIM + eps*8);
        float4 v0 = row[0], v1 = row[1];
        int c0 = eps*8;
        hbuf[(c0+0)*64 + pe] = v0.x; hbuf[(c0+1)*64 + pe] = v0.y;
        hbuf[(c0+2)*64 + pe] = v0.z; hbuf[(c0+3)*64 + pe] = v0.w;
        hbuf[(c0+4)*64 + pe] = v1.x; hbuf[(c0+5)*64 + pe] = v1.y;
        hbuf[(c0+6)*64 + pe] = v1.z; hbuf[(c0+7)*64 + pe] = v1.w;
    }
    __syncthreads();

    int cur = 0;
    int jb0 = eps*2;
    #pragma unroll 1
    for (int s = 0; s < PLEN; ++s) {
        int l = link_to_path[pp*PLEN + s];
        bool nz = act && (nzf[l] != 0);
        const float* G = Gi + (size_t)l * GCOLS;
        const float* hold = hbuf + cur*(DPDIM*64) + pe;
        float* hnew = hbuf + (cur^1)*(DPDIM*64) + pe;
        #pragma unroll 1
        for (int jj = 0; jj < 2; ++jj) {
            int jb = jb0 + jj;                               // wave-uniform
            float4 az  = *(const float4*)(G + jb*4);
            float4 ar  = *(const float4*)(G + 32 + jb*4);
            float4 gih = *(const float4*)(G + 64 + jb*4);
            float4 ah  = *(const float4*)(bhp + 64 + jb*4);  // uniform s_load
            const float* w = UpT + jb*(32*12);               // uniform s_load
            #pragma unroll 4
            for (int k = 0; k < DPDIM; ++k) {
                float hk = hold[k*64];
                const float4 wz = *(const float4*)(w);
                const float4 wr = *(const float4*)(w + 4);
                const float4 wh = *(const float4*)(w + 8);
                ACC4F(az, hk, wz); ACC4F(ar, hk, wr); ACC4F(ah, hk, wh);
                w += 12;
            }
#define PWC(C, j) { \
            float zz = fast_sigmoid(az.C); \
            float rr = fast_sigmoid(ar.C); \
            float cc = fast_tanh(gih.C + rr * ah.C); \
            float ho = hold[(jb*4+j)*64]; \
            hnew[(jb*4+j)*64] = nz ? (cc + zz * (ho - cc)) : ho; }
            PWC(x, 0) PWC(y, 1) PWC(z, 2) PWC(w, 3)
#undef PWC
        }
        __syncthreads();     // hnew complete + hold reads done across waves
        cur ^= 1;
    }

    if (act) {
        const float* hf = hbuf + cur*(DPDIM*64) + pe;
        int c0 = eps*8;
        float4 a = make_float4(hf[(c0+0)*64], hf[(c0+1)*64],
                               hf[(c0+2)*64], hf[(c0+3)*64]);
        float4 b = make_float4(hf[(c0+4)*64], hf[(c0+5)*64],
                               hf[(c0+6)*64], hf[(c0+7)*64]);
        *(float4*)(path_state + (size_t)p * DPDIM + c0)     = a;
        *(float4*)(path_state + (size_t)p * DPDIM + c0 + 4) = b;
    }
}

// ---------------- segment sum: path states -> per-link sums ----------------
__global__ __launch_bounds__(256) void seg_sum_kernel(
    const float* __restrict__ path_state, const int* __restrict__ offsets,
    const int* __restrict__ entries, float* __restrict__ path_sum, int n_links)
{
    int t = threadIdx.x;
    int d = t & 31, li = t >> 5;        // 8 links per block, 32 dims each
    int l = blockIdx.x * 8 + li;
    if (l >= n_links) return;
    int beg = offsets[l], end = offsets[l+1];
    float a0 = 0.f, a1 = 0.f, a2 = 0.f, a3 = 0.f;
    int q = beg;
    for (; q + 3 < end; q += 4) {
        int p0 = entries[q], p1 = entries[q+1], p2 = entries[q+2], p3 = entries[q+3];
        a0 += path_state[(size_t)p0 * DPDIM + d];
        a1 += path_state[(size_t)p1 * DPDIM + d];
        a2 += path_state[(size_t)p2 * DPDIM + d];
        a3 += path_state[(size_t)p3 * DPDIM + d];
    }
    for (; q < end; ++q)
        a0 += path_state[(size_t)entries[q] * DPDIM + d];
    path_sum[(size_t)l * DPDIM + d] = (a0 + a1) + (a2 + a3);
}

// ---------------- link GRU: column-split, 4 waves per block ----------------
// 64 links/block; wave eps owns h-cols [8eps,8eps+8) = jb {2eps,2eps+1}.
// x (=path_sum) and h staged in [col][lane] LDS; weights via WlT/UlT scalar
// loads. Per-k order: az += xk*Wz; az += hk*Uz (matches old gru_step
// bit-for-bit); ai = x-only, ah = h-only; h' = z*ho + (1-z)*c.
__global__ __launch_bounds__(256, 1) void link_kernel(
    const float* __restrict__ path_sum, float* __restrict__ link_state,
    const float* __restrict__ WlT, const float* __restrict__ UlT,
    const float* __restrict__ bil, const float* __restrict__ bhl, int n_links)
{
    __shared__ float xbuf[DPDIM*64];   // 8 KB [col][lane]
    __shared__ float hbuf[DPDIM*64];   // 8 KB [col][lane]
    int t = threadIdx.x;
    int pe = t & 63;
    int eps = __builtin_amdgcn_readfirstlane(t >> 6);
    int l = blockIdx.x * 64 + pe;
    bool act = l < n_links;
    int ll = act ? l : (n_links - 1);
    int c0 = eps*8;
    {
        const float4* xr = (const float4*)(path_sum  + (size_t)ll * DPDIM + c0);
        const float4* hr = (const float4*)(link_state + (size_t)ll * DPDIM + c0);
        float4 x0 = xr[0], x1 = xr[1], h0 = hr[0], h1 = hr[1];
        xbuf[(c0+0)*64 + pe] = x0.x; xbuf[(c0+1)*64 + pe] = x0.y;
        xbuf[(c0+2)*64 + pe] = x0.z; xbuf[(c0+3)*64 + pe] = x0.w;
        xbuf[(c0+4)*64 + pe] = x1.x; xbuf[(c0+5)*64 + pe] = x1.y;
        xbuf[(c0+6)*64 + pe] = x1.z; xbuf[(c0+7)*64 + pe] = x1.w;
        hbuf[(c0+0)*64 + pe] = h0.x; hbuf[(c0+1)*64 + pe] = h0.y;
        hbuf[(c0+2)*64 + pe] = h0.z; hbuf[(c0+3)*64 + pe] = h0.w;
        hbuf[(c0+4)*64 + pe] = h1.x; hbuf[(c0+5)*64 + pe] = h1.y;
        hbuf[(c0+6)*64 + pe] = h1.z; hbuf[(c0+7)*64 + pe] = h1.w;
    }
    __syncthreads();

    int jb0 = eps*2;
    #pragma unroll 1
    for (int jj = 0; jj < 2; ++jj) {
        int jb = jb0 + jj;                               // wave-uniform
        float4 az = {0,0,0,0}, ar = {0,0,0,0}, ai = {0,0,0,0}, ah = {0,0,0,0};
        const float* w = WlT + jb*(32*12);               // uniform s_load
        const float* u = UlT + jb*(32*12);               // uniform s_load
        #pragma unroll 4
        for (int k = 0; k < DPDIM; ++k) {
            float xk = xbuf[k*64 + pe];
            float hk = hbuf[k*64 + pe];
            const float4 wz = *(const float4*)(w);
            const float4 wr = *(const float4*)(w + 4);
            const float4 wh = *(const float4*)(w + 8);
            const float4 uz = *(const float4*)(u);
            const float4 ur = *(const float4*)(u + 4);
            const float4 uh = *(const float4*)(u + 8);
            ACC4F(az, xk, wz); ACC4F(az, hk, uz);
            ACC4F(ar, xk, wr); ACC4F(ar, hk, ur);
            ACC4F(ai, xk, wh);
            ACC4F(ah, hk, uh);
            w += 12; u += 12;
        }
        const float4 BZI = *(const float4*)(bil + jb*4);
        const float4 BRI = *(const float4*)(bil + 32 + jb*4);
        const float4 BHI = *(const float4*)(bil + 64 + jb*4);
        const float4 BZH = *(const float4*)(bhl + jb*4);
        const float4 BRH = *(const float4*)(bhl + 32 + jb*4);
        const float4 BHH = *(const float4*)(bhl + 64 + jb*4);
        float4 hv;
#define LWC(C, j, DST) { \
        float z = fast_sigmoid(az.C + BZI.C + BZH.C); \
        float r = fast_sigmoid(ar.C + BRI.C + BRH.C); \
        float c = fast_tanh(ai.C + BHI.C + r * (ah.C + BHH.C)); \
        float ho = hbuf[(jb*4+j)*64 + pe]; \
        DST = z*ho + (1.f - z)*c; }
        LWC(x, 0, hv.x) LWC(y, 1, hv.y) LWC(z, 2, hv.z) LWC(w, 3, hv.w)
#undef LWC
        if (act) *(float4*)(link_state + (size_t)ll * DPDIM + jb*4) = hv;
    }
}

// ---------------- readout: lane=link, scalar weights -----------------------
// 512 threads = 8 waves; wave g owns cols [32g,32g+32); lane u owns link
// l0+u. r1 values exchanged through 257-padded LDS (per-lane reads, bank
// conflict-free); W1/W2/b*/W3 are wave-uniform scalar loads (s_load), so the
// r2 GEMM runs 1 ds_read_b32 per k feeding 32 FMAs (was 1:1 broadcast reads
// -> LDS-pipe bound at 160us).
__global__ __launch_bounds__(512, 1) void readout_kernel(
    const float* __restrict__ link_state,
    const float* __restrict__ W1, const float* __restrict__ b1,
    const float* __restrict__ W2, const float* __restrict__ b2,
    const float* __restrict__ W3, const float* __restrict__ b3,
    float* __restrict__ out, int n_links)
{
    __shared__ float s_m[64*257];     // 64.25 KB, r1[link][col] (pad 257)
    __shared__ float s_part[8*64];
    int t = threadIdx.x;
    int u = t & 63;                                     // link lane
    int g = __builtin_amdgcn_readfirstlane(t >> 6);     // wave id 0..7
    int l = blockIdx.x * 64 + u;
    bool act = l < n_links;
    int ll = act ? l : (n_links - 1);

    float x[DPDIM];
    {
        const float4* row = (const float4*)(link_state + (size_t)ll * DPDIM);
        #pragma unroll
        for (int k4 = 0; k4 < 8; ++k4) {
            float4 v = row[k4];
            x[4*k4+0]=v.x; x[4*k4+1]=v.y; x[4*k4+2]=v.z; x[4*k4+3]=v.w;
        }
    }
    // r1 for cols [32g, 32g+32): acc1 = b1 then k-ascending FMA (old order)
    {
        const float* w1p = W1 + 32*g;                   // uniform base
        const float* b1p = b1 + 32*g;
        float acc1[32];
        #pragma unroll
        for (int c = 0; c < 32; ++c) acc1[c] = b1p[c];
        #pragma unroll 2
        for (int k = 0; k < DPDIM; ++k) {
            float xk = x[k];
            #pragma unroll
            for (int c = 0; c < 32; ++c)
                acc1[c] = fmaf(xk, w1p[k*RUNITS + c], acc1[c]);
        }
        #pragma unroll
        for (int c = 0; c < 32; ++c)
            s_m[u*257 + 32*g + c] = fmaxf(acc1[c], 0.f);
    }
    __syncthreads();
    // r2 for cols [32g,32g+32) of link u: 1 LDS read per k -> 32 FMA
    float acc[32];
    {
        const float* w2p = W2 + 32*g;                   // uniform base
        const float* b2p = b2 + 32*g;
        #pragma unroll
        for (int c = 0; c < 32; ++c) acc[c] = b2p[c];
        const float* rrow = s_m + u*257;
        #pragma unroll 2
        for (int k = 0; k < RUNITS; ++k) {
            float rk = rrow[k];
            #pragma unroll
            for (int c = 0; c < 32; ++c)
                acc[c] = fmaf(rk, w2p[k*RUNITS + c], acc[c]);
        }
    }
    // partial dot with w3 (cols ascending within wave = old quarter order)
    {
        const float* w3p = W3 + 32*g;
        float psum = 0.f;
        #pragma unroll
        for (int c = 0; c < 32; ++c)
            psum += fmaxf(acc[c], 0.f) * w3p[c];
        s_part[g*64 + u] = psum;
    }
    __syncthreads();
    if (t < 64 && act) {
        float ssum = b3[0];
        #pragma unroll
        for (int gg = 0; gg < 8; ++gg) ssum += s_part[gg*64 + u];
        out[l] = ssum;
    }
}

// ---------------- launch ----------------
extern "C" void kernel_launch(void* const* d_in, const int* in_sizes, int n_in,
                              void* d_out, int out_size, void* d_ws, size_t ws_size,
                              hipStream_t stream)
{
    const float* traffic  = (const float*)d_in[0];
    const float* packets  = (const float*)d_in[1];
    const float* eqlam    = (const float*)d_in[2];
    const float* avgpkt   = (const float*)d_in[3];
    const float* capacity = (const float*)d_in[4];
    const float* queues   = (const float*)d_in[5];
    const int* link_to_path = (const int*)d_in[6];
    const float* Wp  = (const float*)d_in[13];
    const float* Up  = (const float*)d_in[14];
    const float* bip = (const float*)d_in[15];
    const float* bhp = (const float*)d_in[16];
    const float* Wl  = (const float*)d_in[17];
    const float* Ul  = (const float*)d_in[18];
    const float* bil = (const float*)d_in[19];
    const float* bhl = (const float*)d_in[20];
    const float* W1  = (const float*)d_in[21];
    const float* b1  = (const float*)d_in[22];
    const float* W2  = (const float*)d_in[23];
    const float* b2  = (const float*)d_in[24];
    const float* W3  = (const float*)d_in[25];
    const float* b3  = (const float*)d_in[26];
    const int n_paths = in_sizes[0];     // 100000
    const int n_links = in_sizes[4];     // 20000
    const int n_ent   = in_sizes[6];     // 800000

    char* ws = (char*)d_ws;
    size_t off = 0;
    auto salloc = [&](size_t bytes) -> void* {
        void* p = ws + off;
        off += (bytes + 255) & ~size_t(255);
        return p;
    };
    float* path_state = (float*)salloc((size_t)n_paths * DPDIM * 4);
    float* link_state = (float*)salloc((size_t)n_links * DPDIM * 4);
    float* Gi         = (float*)salloc((size_t)n_links * GCOLS * 4);
    float* path_sum   = Gi;
    float* UpT   = (float*)salloc((size_t)8 * 32 * 12 * 4);
    float* WpT   = (float*)salloc((size_t)8 * 32 * 12 * 4);
    float* WlT   = (float*)salloc((size_t)8 * 32 * 12 * 4);
    float* UlT   = (float*)salloc((size_t)8 * 32 * 12 * 4);
    int* nzf     = (int*)salloc((size_t)n_links * 4);
    int* counts  = (int*)salloc((size_t)n_links * 4);
    int* offsets = (int*)salloc((size_t)(n_links + 1) * 4);
    int* cursor  = (int*)salloc((size_t)n_links * 4);
    int* entries = (int*)salloc((size_t)n_ent * 4);
    (void)ws_size; (void)n_in; (void)out_size;

    int gmax = ( (n_paths > n_links ? n_paths : n_links) + 255 ) / 256;
    zero_counts_kernel<<<(n_links + 255)/256, 256, 0, stream>>>(counts, n_links);
    init_kernel<<<gmax, 256, 0, stream>>>(traffic, packets, eqlam, avgpkt,
                                          capacity, queues, path_state, link_state,
                                          n_paths, n_links);
    transpose_w_kernel<<<(8*32*12 + 255)/256, 256, 0, stream>>>(Up, UpT);
    transpose_w_kernel<<<(8*32*12 + 255)/256, 256, 0, stream>>>(Wp, WpT);
    transpose_w_kernel<<<(8*32*12 + 255)/256, 256, 0, stream>>>(Wl, WlT);
    transpose_w_kernel<<<(8*32*12 + 255)/256, 256, 0, stream>>>(Ul, UlT);
    hist_kernel<<<(n_ent + 255)/256, 256, 0, stream>>>(link_to_path, counts, n_ent);
    scan_kernel<<<1, 1024, 0, stream>>>(counts, offsets, cursor, n_links);
    fill_kernel<<<(n_ent + 255)/256, 256, 0, stream>>>(link_to_path, cursor, entries, n_ent);

    int lgrid = (n_links + 63) / 64;
    for (int it = 0; it < T_ITERS; ++it) {
        gate_pre_kernel<<<lgrid, 256, 0, stream>>>(
            link_state, WpT, bip, bhp, Gi, nzf, n_links);
        path_kernel<<<(n_paths + 63)/64, 256, 0, stream>>>(
            Gi, nzf, path_state, link_to_path, UpT, bhp, n_paths);
        seg_sum_kernel<<<(n_links + 7)/8, 256, 0, stream>>>(
            path_state, offsets, entries, path_sum, n_links);
        link_kernel<<<lgrid, 256, 0, stream>>>(
            path_sum, link_state, WlT, UlT, bil, bhl, n_links);
    }
    readout_kernel<<<lgrid, 512, 0, stream>>>(
        link_state, W1, b1, W2, b2, W3, b3, (float*)d_out, n_links);
}